// Round 8
// baseline (322.065 us; speedup 1.0000x reference)
//
#include <hip/hip_runtime.h>
#include <hip/hip_bf16.h>
#include <cstdint>

#define S_LEN 4096
#define NHEAD 4
#define HDIM 32
#define HID 128
#define CBATCH 4
#define EPSW 1e-8f

typedef __attribute__((ext_vector_type(8))) short short8v;
typedef __attribute__((ext_vector_type(4))) float float4v;

__device__ __forceinline__ unsigned short f2bf(float f) {
    unsigned int u = __float_as_uint(f);
    return (unsigned short)((u + 0x7fffu + ((u >> 16) & 1u)) >> 16);
}

__device__ __forceinline__ float exp2_asm(float x) {
    float r;
    asm("v_exp_f32 %0, %1" : "=v"(r) : "v"(x));
    return r;
}

__device__ __forceinline__ unsigned cvt_pk_bf16(float lo, float hi) {
    unsigned r;
    asm("v_cvt_pk_bf16_f32 %0, %1, %2" : "=v"(r) : "v"(lo), "v"(hi));
    return r;
}

// ---------------------------------------------------------------------------
// Kernel 1: fused QKV projection.  out = (x @ W.T + b) [* SCALE*log2e for Q]
// ---------------------------------------------------------------------------
__global__ __launch_bounds__(256) void qkv_proj_kernel(
    const float* __restrict__ x,
    const float* __restrict__ Wq, const float* __restrict__ bq,
    const float* __restrict__ Wk, const float* __restrict__ bk,
    const float* __restrict__ Wv, const float* __restrict__ bv,
    unsigned short* __restrict__ Qo, unsigned short* __restrict__ Ko,
    unsigned short* __restrict__ Vo)
{
    __shared__ float xs[64][132];
    __shared__ float wsT[64][68];

    const int tid = threadIdx.x;
    const int mrow0 = blockIdx.x * 64;
    const int n0 = blockIdx.y * 64;
    const int p = blockIdx.z;
    const float* W    = (p == 0) ? Wq : (p == 1) ? Wk : Wv;
    const float* bias = (p == 0) ? bq : (p == 1) ? bk : bv;
    unsigned short* Out = (p == 0) ? Qo : (p == 1) ? Ko : Vo;

    for (int i = tid; i < 64 * 32; i += 256) {
        int r = i >> 5, c4 = (i & 31) * 4;
        *(float4*)&xs[r][c4] = *(const float4*)&x[(size_t)(mrow0 + r) * HID + c4];
    }

    float acc[4][4] = {};
    const int tr = tid >> 4;
    const int tc = tid & 15;

    for (int ph = 0; ph < 2; ++ph) {
        __syncthreads();
        for (int i = tid; i < 64 * 16; i += 256) {
            int r = i >> 4, c4 = (i & 15) * 4;
            float4 wv = *(const float4*)&W[(size_t)(n0 + r) * HID + ph * 64 + c4];
            wsT[c4 + 0][r] = wv.x;
            wsT[c4 + 1][r] = wv.y;
            wsT[c4 + 2][r] = wv.z;
            wsT[c4 + 3][r] = wv.w;
        }
        __syncthreads();
        #pragma unroll 4
        for (int k4 = 0; k4 < 16; ++k4) {
            float4 xv[4];
            #pragma unroll
            for (int i = 0; i < 4; ++i)
                xv[i] = *(const float4*)&xs[tr * 4 + i][ph * 64 + k4 * 4];
            #pragma unroll
            for (int kk = 0; kk < 4; ++kk) {
                float4 wv = *(const float4*)&wsT[k4 * 4 + kk][tc * 4];
                #pragma unroll
                for (int i = 0; i < 4; ++i) {
                    float xk = ((const float*)&xv[i])[kk];
                    acc[i][0] += xk * wv.x;
                    acc[i][1] += xk * wv.y;
                    acc[i][2] += xk * wv.z;
                    acc[i][3] += xk * wv.w;
                }
            }
        }
    }

    // SCALE * log2(e): exp(s*SCALE) == exp2(s * SCALE * log2e)
    const float scale = (p == 0) ? 0.25500544458521289f : 1.0f;
    float4 bv4 = *(const float4*)&bias[n0 + tc * 4];
    const int nbase = n0 + tc * 4;
    const int h = nbase >> 5;
    const int d = nbase & 31;
    #pragma unroll
    for (int i = 0; i < 4; ++i) {
        int m = mrow0 + tr * 4 + i;
        int c = m >> 12, s = m & 4095;
        unsigned short pk[4];
        pk[0] = f2bf((acc[i][0] + bv4.x) * scale);
        pk[1] = f2bf((acc[i][1] + bv4.y) * scale);
        pk[2] = f2bf((acc[i][2] + bv4.z) * scale);
        pk[3] = f2bf((acc[i][3] + bv4.w) * scale);
        *(uint2*)&Out[((size_t)(c * NHEAD + h) * S_LEN + s) * HDIM + d] = *(uint2*)pk;
    }
}

// ---------------------------------------------------------------------------
// Kernel 2: transpose V (C,NH,S,HD) -> Vt (C,NH,HD,S), bf16.  [validated]
// ---------------------------------------------------------------------------
__global__ __launch_bounds__(256) void vtrans_kernel(
    const unsigned short* __restrict__ V, unsigned short* __restrict__ Vt)
{
    __shared__ unsigned short vs[64][40];
    const int tid = threadIdx.x;
    const int chh = blockIdx.y;
    const int s0 = blockIdx.x * 64;
    const size_t base = (size_t)chh * S_LEN * HDIM;
    {
        int r = tid >> 2, ch = (tid & 3) * 8;
        *(uint4*)&vs[r][ch] = *(const uint4*)&V[base + (size_t)(s0 + r) * HDIM + ch];
    }
    __syncthreads();
    {
        int dd = tid >> 3, chs = (tid & 7) * 8;
        unsigned short pk[8];
        #pragma unroll
        for (int j = 0; j < 8; ++j) pk[j] = vs[chs + j][dd];
        *(uint4*)&Vt[(size_t)chh * HDIM * S_LEN + (size_t)dd * S_LEN + s0 + chs] = *(uint4*)pk;
    }
}

// ---------------------------------------------------------------------------
// Kernel 3: attention, split-K (templated NS), dual q-subtile [r4 body]
// + 1-deep register prefetch of the ew stream.
// NOTE: __launch_bounds__(256) ONLY — the (256,4) min-waves variant
// miscompiled/corrupted in r3/r5/r6/r7 (7/7 correlation with failures).
// ---------------------------------------------------------------------------
template<int NS>
__global__ __launch_bounds__(256) void attn_kernel(
    const unsigned short* __restrict__ Q, const unsigned short* __restrict__ K,
    const unsigned short* __restrict__ Vt, const float* __restrict__ ew,
    float* __restrict__ partO, float* __restrict__ den)
{
    const int KCHUNK = S_LEN / NS;
    const int NIT = KCHUNK / 32;

    const int tid = threadIdx.x;
    const int w = tid >> 6;          // head
    const int lane = tid & 63;
    const int li = lane & 15;
    const int g = lane >> 4;
    const int c = blockIdx.y;
    const int qbase = blockIdx.x * 32;
    const int split = blockIdx.z;
    const int kb0 = split * KCHUNK;
    const int chh = c * NHEAD + w;

    const size_t hb = (size_t)chh * S_LEN * HDIM;
    const unsigned short* Qh = Q + hb;

    short8v qf0 = *(const short8v*)&Qh[(size_t)(qbase + li) * HDIM + g * 8];
    short8v qf1 = *(const short8v*)&Qh[(size_t)(qbase + 16 + li) * HDIM + g * 8];

    const unsigned short* kp  = K + hb + (size_t)(kb0 + li) * HDIM + g * 8;
    const unsigned short* vp0 = Vt + hb + (size_t)li * S_LEN + kb0 + g * 4;        // d = li
    const unsigned short* vp1 = vp0 + (size_t)16 * S_LEN;                          // d = 16+li
    const float* ep0 = ew + (size_t)c * S_LEN * S_LEN + (size_t)(qbase + li) * S_LEN + kb0 + g * 4;
    const float* ep1 = ep0 + (size_t)16 * S_LEN;

    float4v o00 = {}, o01 = {}, o10 = {}, o11 = {};
    float den0 = 0.f, den1 = 0.f;
    const float4v zero4 = {0.f, 0.f, 0.f, 0.f};

    // prologue: current-iteration ew in registers
    float4 e00 = *(const float4*)ep0;
    float4 e01 = *(const float4*)(ep0 + 16);
    float4 e10 = *(const float4*)ep1;
    float4 e11 = *(const float4*)(ep1 + 16);

    #pragma unroll 2
    for (int it = 0; it < NIT; ++it) {
        // prefetch next iteration's ew (clamped on last iter)
        const float* np0 = (it + 1 < NIT) ? ep0 + 32 : ep0;
        const float* np1 = (it + 1 < NIT) ? ep1 + 32 : ep1;
        float4 ne00 = *(const float4*)np0;
        float4 ne01 = *(const float4*)(np0 + 16);
        float4 ne10 = *(const float4*)np1;
        float4 ne11 = *(const float4*)(np1 + 16);

        short8v kf0 = *(const short8v*)kp;
        short8v kf1 = *(const short8v*)(kp + 512);

        union { short8v v; uint2 u2[2]; } v0, v1;
        v0.u2[0] = *(const uint2*)vp0;
        v0.u2[1] = *(const uint2*)(vp0 + 16);
        v1.u2[0] = *(const uint2*)vp1;
        v1.u2[1] = *(const uint2*)(vp1 + 16);

        float4v s0 = __builtin_amdgcn_mfma_f32_16x16x32_bf16(kf0, qf0, zero4, 0, 0, 0);
        float4v s1 = __builtin_amdgcn_mfma_f32_16x16x32_bf16(kf1, qf0, zero4, 0, 0, 0);
        float4v s2 = __builtin_amdgcn_mfma_f32_16x16x32_bf16(kf0, qf1, zero4, 0, 0, 0);
        float4v s3 = __builtin_amdgcn_mfma_f32_16x16x32_bf16(kf1, qf1, zero4, 0, 0, 0);

        float p0 = fmaxf(e00.x, EPSW) * exp2_asm(s0[0]);
        float p1 = fmaxf(e00.y, EPSW) * exp2_asm(s0[1]);
        float p2 = fmaxf(e00.z, EPSW) * exp2_asm(s0[2]);
        float p3 = fmaxf(e00.w, EPSW) * exp2_asm(s0[3]);
        float p4 = fmaxf(e01.x, EPSW) * exp2_asm(s1[0]);
        float p5 = fmaxf(e01.y, EPSW) * exp2_asm(s1[1]);
        float p6 = fmaxf(e01.z, EPSW) * exp2_asm(s1[2]);
        float p7 = fmaxf(e01.w, EPSW) * exp2_asm(s1[3]);
        union { short8v v; unsigned u[4]; } pu0;
        pu0.u[0] = cvt_pk_bf16(p0, p1);
        pu0.u[1] = cvt_pk_bf16(p2, p3);
        pu0.u[2] = cvt_pk_bf16(p4, p5);
        pu0.u[3] = cvt_pk_bf16(p6, p7);
        den0 += ((p0 + p1) + (p2 + p3)) + ((p4 + p5) + (p6 + p7));
        o00 = __builtin_amdgcn_mfma_f32_16x16x32_bf16(v0.v, pu0.v, o00, 0, 0, 0);
        o01 = __builtin_amdgcn_mfma_f32_16x16x32_bf16(v1.v, pu0.v, o01, 0, 0, 0);

        float r0 = fmaxf(e10.x, EPSW) * exp2_asm(s2[0]);
        float r1 = fmaxf(e10.y, EPSW) * exp2_asm(s2[1]);
        float r2 = fmaxf(e10.z, EPSW) * exp2_asm(s2[2]);
        float r3 = fmaxf(e10.w, EPSW) * exp2_asm(s2[3]);
        float r4 = fmaxf(e11.x, EPSW) * exp2_asm(s3[0]);
        float r5 = fmaxf(e11.y, EPSW) * exp2_asm(s3[1]);
        float r6 = fmaxf(e11.z, EPSW) * exp2_asm(s3[2]);
        float r7 = fmaxf(e11.w, EPSW) * exp2_asm(s3[3]);
        union { short8v v; unsigned u[4]; } pu1;
        pu1.u[0] = cvt_pk_bf16(r0, r1);
        pu1.u[1] = cvt_pk_bf16(r2, r3);
        pu1.u[2] = cvt_pk_bf16(r4, r5);
        pu1.u[3] = cvt_pk_bf16(r6, r7);
        den1 += ((r0 + r1) + (r2 + r3)) + ((r4 + r5) + (r6 + r7));
        o10 = __builtin_amdgcn_mfma_f32_16x16x32_bf16(v0.v, pu1.v, o10, 0, 0, 0);
        o11 = __builtin_amdgcn_mfma_f32_16x16x32_bf16(v1.v, pu1.v, o11, 0, 0, 0);

        // rotate prefetched ew into place; advance pointers
        e00 = ne00; e01 = ne01; e10 = ne10; e11 = ne11;
        kp += 1024;       // 32 keys * 32 dims
        vp0 += 32;
        vp1 += 32;
        ep0 += 32;
        ep1 += 32;
    }

    den0 += __shfl_xor(den0, 16, 64);
    den0 += __shfl_xor(den0, 32, 64);
    den1 += __shfl_xor(den1, 16, 64);
    den1 += __shfl_xor(den1, 32, 64);

    const size_t pbase = (((size_t)split * CBATCH + c) * NHEAD + w) * S_LEN + qbase;
    {
        const size_t pb = pbase + li;
        float4 o;
        o.x = o00[0]; o.y = o00[1]; o.z = o00[2]; o.w = o00[3];
        *(float4*)&partO[pb * HDIM + 0 * 16 + g * 4] = o;
        o.x = o01[0]; o.y = o01[1]; o.z = o01[2]; o.w = o01[3];
        *(float4*)&partO[pb * HDIM + 1 * 16 + g * 4] = o;
        if (g == 0) den[pb] = den0;
    }
    {
        const size_t pb = pbase + 16 + li;
        float4 o;
        o.x = o10[0]; o.y = o10[1]; o.z = o10[2]; o.w = o10[3];
        *(float4*)&partO[pb * HDIM + 0 * 16 + g * 4] = o;
        o.x = o11[0]; o.y = o11[1]; o.z = o11[2]; o.w = o11[3];
        *(float4*)&partO[pb * HDIM + 1 * 16 + g * 4] = o;
        if (g == 0) den[pb] = den1;
    }
}

// ---------------------------------------------------------------------------
// Kernel 4: combine NS splits -> normalized attention output (C,S,HID) fp32.
// ---------------------------------------------------------------------------
template<int NS>
__global__ __launch_bounds__(256) void combine_kernel(
    const float* __restrict__ pO, const float* __restrict__ den,
    float* __restrict__ attnbuf)
{
    const int idx = blockIdx.x * 256 + threadIdx.x;
    const int d4 = idx & 7;
    const int q  = (idx >> 3) & (S_LEN - 1);
    const int h  = (idx >> 15) & 3;
    const int c  = idx >> 17;

    const size_t bq = ((size_t)c * NHEAD + h) * S_LEN + q;
    const size_t plane = (size_t)CBATCH * NHEAD * S_LEN;
    float4 acc = {0.f, 0.f, 0.f, 0.f};
    float dsum = 0.f;
    #pragma unroll
    for (int s = 0; s < NS; ++s) {
        const size_t b = (size_t)s * plane + bq;
        float4 a = *(const float4*)&pO[b * HDIM + d4 * 4];
        acc.x += a.x; acc.y += a.y; acc.z += a.z; acc.w += a.w;
        dsum += den[b];
    }
    float inv = 1.0f / dsum;
    float4 o;
    o.x = acc.x * inv;
    o.y = acc.y * inv;
    o.z = acc.z * inv;
    o.w = acc.w * inv;
    *(float4*)&attnbuf[((size_t)c * S_LEN + q) * HID + h * HDIM + d4 * 4] = o;
}

// ---------------------------------------------------------------------------
// Kernel 5: output projection. out = attnbuf @ Wo.T + bo   (all fp32)
// ---------------------------------------------------------------------------
__global__ __launch_bounds__(256) void out_proj_kernel(
    const float* __restrict__ ain, const float* __restrict__ Wo,
    const float* __restrict__ bo, float* __restrict__ out)
{
    __shared__ float xs[64][132];
    __shared__ float wsT[64][68];

    const int tid = threadIdx.x;
    const int mrow0 = blockIdx.x * 64;
    const int n0 = blockIdx.y * 64;

    for (int i = tid; i < 64 * 32; i += 256) {
        int r = i >> 5, c4 = (i & 31) * 4;
        *(float4*)&xs[r][c4] = *(const float4*)&ain[(size_t)(mrow0 + r) * HID + c4];
    }

    float acc[4][4] = {};
    const int tr = tid >> 4;
    const int tc = tid & 15;

    for (int ph = 0; ph < 2; ++ph) {
        __syncthreads();
        for (int i = tid; i < 64 * 16; i += 256) {
            int r = i >> 4, c4 = (i & 15) * 4;
            float4 wv = *(const float4*)&Wo[(size_t)(n0 + r) * HID + ph * 64 + c4];
            wsT[c4 + 0][r] = wv.x;
            wsT[c4 + 1][r] = wv.y;
            wsT[c4 + 2][r] = wv.z;
            wsT[c4 + 3][r] = wv.w;
        }
        __syncthreads();
        #pragma unroll 4
        for (int k4 = 0; k4 < 16; ++k4) {
            float4 xv[4];
            #pragma unroll
            for (int i = 0; i < 4; ++i)
                xv[i] = *(const float4*)&xs[tr * 4 + i][ph * 64 + k4 * 4];
            #pragma unroll
            for (int kk = 0; kk < 4; ++kk) {
                float4 wv = *(const float4*)&wsT[k4 * 4 + kk][tc * 4];
                #pragma unroll
                for (int i = 0; i < 4; ++i) {
                    float xk = ((const float*)&xv[i])[kk];
                    acc[i][0] += xk * wv.x;
                    acc[i][1] += xk * wv.y;
                    acc[i][2] += xk * wv.z;
                    acc[i][3] += xk * wv.w;
                }
            }
        }
    }

    float4 bv4 = *(const float4*)&bo[n0 + tc * 4];
    #pragma unroll
    for (int i = 0; i < 4; ++i) {
        int m = mrow0 + tr * 4 + i;
        float4 o;
        o.x = acc[i][0] + bv4.x;
        o.y = acc[i][1] + bv4.y;
        o.z = acc[i][2] + bv4.z;
        o.w = acc[i][3] + bv4.w;
        *(float4*)&out[(size_t)m * HID + n0 + tc * 4] = o;
    }
}

extern "C" void kernel_launch(void* const* d_in, const int* in_sizes, int n_in,
                              void* d_out, int out_size, void* d_ws, size_t ws_size,
                              hipStream_t stream) {
    const float* x  = (const float*)d_in[0];
    const float* ew = (const float*)d_in[1];
    const float* Wq = (const float*)d_in[2];
    const float* bq = (const float*)d_in[3];
    const float* Wk = (const float*)d_in[4];
    const float* bk = (const float*)d_in[5];
    const float* Wv = (const float*)d_in[6];
    const float* bv = (const float*)d_in[7];
    const float* Wo = (const float*)d_in[8];
    const float* bo = (const float*)d_in[9];
    float* out = (float*)d_out;

    char* ws = (char*)d_ws;
    const size_t QSZ = (size_t)CBATCH * NHEAD * S_LEN * HDIM * sizeof(unsigned short); // 4 MiB
    const size_t PLANE_O = (size_t)CBATCH * NHEAD * S_LEN * HDIM * sizeof(float);      // 8 MiB
    const size_t PLANE_D = (size_t)CBATCH * NHEAD * S_LEN * sizeof(float);             // 256 KiB

    // choose NSPLIT by workspace capacity (deterministic: ws_size fixed per run)
    const size_t need4 = 3 * QSZ + 4 * PLANE_O + 4 * PLANE_D;
    const int ns = (ws_size >= need4) ? 4 : 2;

    unsigned short* Qw  = (unsigned short*)(ws);
    unsigned short* Kw  = (unsigned short*)(ws + QSZ);
    unsigned short* Vtw = (unsigned short*)(ws + 2 * QSZ);
    unsigned short* Vw  = (unsigned short*)(ws + 3 * QSZ);
    float* partO = (float*)(ws + 3 * QSZ);                 // overlaps dead Vw
    float* den   = (float*)(ws + 3 * QSZ + (size_t)ns * PLANE_O);
    float* attnbuf = (float*)(ws);                          // overlaps dead Qw/Kw

    qkv_proj_kernel<<<dim3(256, 2, 3), 256, 0, stream>>>(x, Wq, bq, Wk, bk, Wv, bv, Qw, Kw, Vw);
    vtrans_kernel<<<dim3(S_LEN / 64, CBATCH * NHEAD), 256, 0, stream>>>(Vw, Vtw);
    if (ns == 4) {
        attn_kernel<4><<<dim3(S_LEN / 32, CBATCH, 4), 256, 0, stream>>>(Qw, Kw, Vtw, ew, partO, den);
        combine_kernel<4><<<dim3((CBATCH * S_LEN * HID / 4) / 256), 256, 0, stream>>>(partO, den, attnbuf);
    } else {
        attn_kernel<2><<<dim3(S_LEN / 32, CBATCH, 2), 256, 0, stream>>>(Qw, Kw, Vtw, ew, partO, den);
        combine_kernel<2><<<dim3((CBATCH * S_LEN * HID / 4) / 256), 256, 0, stream>>>(partO, den, attnbuf);
    }
    out_proj_kernel<<<dim3(256, 2), 256, 0, stream>>>(attnbuf, Wo, bo, out);
}

// Round 9
// 266.321 us; speedup vs baseline: 1.2093x; 1.2093x over previous
//
#include <hip/hip_runtime.h>
#include <hip/hip_bf16.h>
#include <cstdint>

#define S_LEN 4096
#define NHEAD 4
#define HDIM 32
#define HID 128
#define CBATCH 4
#define EPSW 1e-8f

typedef __attribute__((ext_vector_type(8))) short short8v;
typedef __attribute__((ext_vector_type(4))) float float4v;

__device__ __forceinline__ unsigned short f2bf(float f) {
    unsigned int u = __float_as_uint(f);
    return (unsigned short)((u + 0x7fffu + ((u >> 16) & 1u)) >> 16);
}

__device__ __forceinline__ float exp2_asm(float x) {
    float r;
    asm("v_exp_f32 %0, %1" : "=v"(r) : "v"(x));
    return r;
}

__device__ __forceinline__ unsigned cvt_pk_bf16(float lo, float hi) {
    unsigned r;
    asm("v_cvt_pk_bf16_f32 %0, %1, %2" : "=v"(r) : "v"(lo), "v"(hi));
    return r;
}

// ---------------------------------------------------------------------------
// Kernel 1: fused QKV projection.  out = (x @ W.T + b) [* SCALE*log2e for Q]
// ---------------------------------------------------------------------------
__global__ __launch_bounds__(256) void qkv_proj_kernel(
    const float* __restrict__ x,
    const float* __restrict__ Wq, const float* __restrict__ bq,
    const float* __restrict__ Wk, const float* __restrict__ bk,
    const float* __restrict__ Wv, const float* __restrict__ bv,
    unsigned short* __restrict__ Qo, unsigned short* __restrict__ Ko,
    unsigned short* __restrict__ Vo)
{
    __shared__ float xs[64][132];
    __shared__ float wsT[64][68];

    const int tid = threadIdx.x;
    const int mrow0 = blockIdx.x * 64;
    const int n0 = blockIdx.y * 64;
    const int p = blockIdx.z;
    const float* W    = (p == 0) ? Wq : (p == 1) ? Wk : Wv;
    const float* bias = (p == 0) ? bq : (p == 1) ? bk : bv;
    unsigned short* Out = (p == 0) ? Qo : (p == 1) ? Ko : Vo;

    for (int i = tid; i < 64 * 32; i += 256) {
        int r = i >> 5, c4 = (i & 31) * 4;
        *(float4*)&xs[r][c4] = *(const float4*)&x[(size_t)(mrow0 + r) * HID + c4];
    }

    float acc[4][4] = {};
    const int tr = tid >> 4;
    const int tc = tid & 15;

    for (int ph = 0; ph < 2; ++ph) {
        __syncthreads();
        for (int i = tid; i < 64 * 16; i += 256) {
            int r = i >> 4, c4 = (i & 15) * 4;
            float4 wv = *(const float4*)&W[(size_t)(n0 + r) * HID + ph * 64 + c4];
            wsT[c4 + 0][r] = wv.x;
            wsT[c4 + 1][r] = wv.y;
            wsT[c4 + 2][r] = wv.z;
            wsT[c4 + 3][r] = wv.w;
        }
        __syncthreads();
        #pragma unroll 4
        for (int k4 = 0; k4 < 16; ++k4) {
            float4 xv[4];
            #pragma unroll
            for (int i = 0; i < 4; ++i)
                xv[i] = *(const float4*)&xs[tr * 4 + i][ph * 64 + k4 * 4];
            #pragma unroll
            for (int kk = 0; kk < 4; ++kk) {
                float4 wv = *(const float4*)&wsT[k4 * 4 + kk][tc * 4];
                #pragma unroll
                for (int i = 0; i < 4; ++i) {
                    float xk = ((const float*)&xv[i])[kk];
                    acc[i][0] += xk * wv.x;
                    acc[i][1] += xk * wv.y;
                    acc[i][2] += xk * wv.z;
                    acc[i][3] += xk * wv.w;
                }
            }
        }
    }

    // SCALE * log2(e): exp(s*SCALE) == exp2(s * SCALE * log2e)
    const float scale = (p == 0) ? 0.25500544458521289f : 1.0f;
    float4 bv4 = *(const float4*)&bias[n0 + tc * 4];
    const int nbase = n0 + tc * 4;
    const int h = nbase >> 5;
    const int d = nbase & 31;
    #pragma unroll
    for (int i = 0; i < 4; ++i) {
        int m = mrow0 + tr * 4 + i;
        int c = m >> 12, s = m & 4095;
        unsigned short pk[4];
        pk[0] = f2bf((acc[i][0] + bv4.x) * scale);
        pk[1] = f2bf((acc[i][1] + bv4.y) * scale);
        pk[2] = f2bf((acc[i][2] + bv4.z) * scale);
        pk[3] = f2bf((acc[i][3] + bv4.w) * scale);
        *(uint2*)&Out[((size_t)(c * NHEAD + h) * S_LEN + s) * HDIM + d] = *(uint2*)pk;
    }
}

// ---------------------------------------------------------------------------
// Kernel 2: transpose V (C,NH,S,HD) -> Vt (C,NH,HD,S), bf16.  [validated]
// ---------------------------------------------------------------------------
__global__ __launch_bounds__(256) void vtrans_kernel(
    const unsigned short* __restrict__ V, unsigned short* __restrict__ Vt)
{
    __shared__ unsigned short vs[64][40];
    const int tid = threadIdx.x;
    const int chh = blockIdx.y;
    const int s0 = blockIdx.x * 64;
    const size_t base = (size_t)chh * S_LEN * HDIM;
    {
        int r = tid >> 2, ch = (tid & 3) * 8;
        *(uint4*)&vs[r][ch] = *(const uint4*)&V[base + (size_t)(s0 + r) * HDIM + ch];
    }
    __syncthreads();
    {
        int dd = tid >> 3, chs = (tid & 7) * 8;
        unsigned short pk[8];
        #pragma unroll
        for (int j = 0; j < 8; ++j) pk[j] = vs[chs + j][dd];
        *(uint4*)&Vt[(size_t)chh * HDIM * S_LEN + (size_t)dd * S_LEN + s0 + chs] = *(uint4*)pk;
    }
}

// ---------------------------------------------------------------------------
// Kernel 3: attention, split-K (templated NS), QUAD q-subtile (QBLK=64).
// Block = (64-query tile, c, split); wave = head.  No LDS, no barriers.
// 4 q-subtiles per wave force VGPR allocation past the 64-reg occupancy
// heuristic -> more loads in flight per wave (r2->r1 scaling law).
// NOTE: plain __launch_bounds__(256) ONLY — (256,4) miscompiles (r3/5/6/7).
// ---------------------------------------------------------------------------
template<int NS>
__global__ __launch_bounds__(256) void attn_kernel(
    const unsigned short* __restrict__ Q, const unsigned short* __restrict__ K,
    const unsigned short* __restrict__ Vt, const float* __restrict__ ew,
    float* __restrict__ partO, float* __restrict__ den)
{
    const int KCHUNK = S_LEN / NS;
    const int NIT = KCHUNK / 32;

    const int tid = threadIdx.x;
    const int w = tid >> 6;          // head
    const int lane = tid & 63;
    const int li = lane & 15;
    const int g = lane >> 4;
    const int c = blockIdx.y;
    const int qbase = blockIdx.x * 64;
    const int split = blockIdx.z;
    const int kb0 = split * KCHUNK;
    const int chh = c * NHEAD + w;

    const size_t hb = (size_t)chh * S_LEN * HDIM;
    const unsigned short* Qh = Q + hb;

    short8v qf[4];
    #pragma unroll
    for (int qs = 0; qs < 4; ++qs)
        qf[qs] = *(const short8v*)&Qh[(size_t)(qbase + qs * 16 + li) * HDIM + g * 8];

    const unsigned short* kp  = K + hb + (size_t)(kb0 + li) * HDIM + g * 8;
    const unsigned short* vp0 = Vt + hb + (size_t)li * S_LEN + kb0 + g * 4;        // d = li
    const unsigned short* vp1 = vp0 + (size_t)16 * S_LEN;                          // d = 16+li
    const float* ep[4];
    ep[0] = ew + (size_t)c * S_LEN * S_LEN + (size_t)(qbase + li) * S_LEN + kb0 + g * 4;
    #pragma unroll
    for (int qs = 1; qs < 4; ++qs) ep[qs] = ep[0] + (size_t)(qs * 16) * S_LEN;

    float4v oacc[4][2] = {};
    float dn[4] = {0.f, 0.f, 0.f, 0.f};
    const float4v zero4 = {0.f, 0.f, 0.f, 0.f};

    for (int it = 0; it < NIT; ++it) {
        // ---- all loads issued up front (independent) ----
        short8v kf0 = *(const short8v*)kp;
        short8v kf1 = *(const short8v*)(kp + 512);

        union { short8v v; uint2 u2[2]; } v0, v1;
        v0.u2[0] = *(const uint2*)vp0;
        v0.u2[1] = *(const uint2*)(vp0 + 16);
        v1.u2[0] = *(const uint2*)vp1;
        v1.u2[1] = *(const uint2*)(vp1 + 16);

        float4 e0[4], e1[4];
        #pragma unroll
        for (int qs = 0; qs < 4; ++qs) {
            e0[qs] = *(const float4*)ep[qs];
            e1[qs] = *(const float4*)(ep[qs] + 16);
        }

        // ---- compute ----
        #pragma unroll
        for (int qs = 0; qs < 4; ++qs) {
            float4v s0 = __builtin_amdgcn_mfma_f32_16x16x32_bf16(kf0, qf[qs], zero4, 0, 0, 0);
            float4v s1 = __builtin_amdgcn_mfma_f32_16x16x32_bf16(kf1, qf[qs], zero4, 0, 0, 0);

            float p0 = fmaxf(e0[qs].x, EPSW) * exp2_asm(s0[0]);
            float p1 = fmaxf(e0[qs].y, EPSW) * exp2_asm(s0[1]);
            float p2 = fmaxf(e0[qs].z, EPSW) * exp2_asm(s0[2]);
            float p3 = fmaxf(e0[qs].w, EPSW) * exp2_asm(s0[3]);
            float p4 = fmaxf(e1[qs].x, EPSW) * exp2_asm(s1[0]);
            float p5 = fmaxf(e1[qs].y, EPSW) * exp2_asm(s1[1]);
            float p6 = fmaxf(e1[qs].z, EPSW) * exp2_asm(s1[2]);
            float p7 = fmaxf(e1[qs].w, EPSW) * exp2_asm(s1[3]);
            union { short8v v; unsigned u[4]; } pu;
            pu.u[0] = cvt_pk_bf16(p0, p1);
            pu.u[1] = cvt_pk_bf16(p2, p3);
            pu.u[2] = cvt_pk_bf16(p4, p5);
            pu.u[3] = cvt_pk_bf16(p6, p7);
            dn[qs] += ((p0 + p1) + (p2 + p3)) + ((p4 + p5) + (p6 + p7));
            oacc[qs][0] = __builtin_amdgcn_mfma_f32_16x16x32_bf16(v0.v, pu.v, oacc[qs][0], 0, 0, 0);
            oacc[qs][1] = __builtin_amdgcn_mfma_f32_16x16x32_bf16(v1.v, pu.v, oacc[qs][1], 0, 0, 0);
        }

        kp += 1024;       // 32 keys * 32 dims
        vp0 += 32;
        vp1 += 32;
        #pragma unroll
        for (int qs = 0; qs < 4; ++qs) ep[qs] += 32;
    }

    const size_t pbase = (((size_t)split * CBATCH + c) * NHEAD + w) * S_LEN + qbase;
    #pragma unroll
    for (int qs = 0; qs < 4; ++qs) {
        float d = dn[qs];
        d += __shfl_xor(d, 16, 64);
        d += __shfl_xor(d, 32, 64);
        const size_t pb = pbase + qs * 16 + li;
        float4 o;
        o.x = oacc[qs][0][0]; o.y = oacc[qs][0][1]; o.z = oacc[qs][0][2]; o.w = oacc[qs][0][3];
        *(float4*)&partO[pb * HDIM + 0 * 16 + g * 4] = o;
        o.x = oacc[qs][1][0]; o.y = oacc[qs][1][1]; o.z = oacc[qs][1][2]; o.w = oacc[qs][1][3];
        *(float4*)&partO[pb * HDIM + 1 * 16 + g * 4] = o;
        if (g == 0) den[pb] = d;
    }
}

// ---------------------------------------------------------------------------
// Kernel 4: combine NS splits -> normalized attention output (C,S,HID) fp32.
// ---------------------------------------------------------------------------
template<int NS>
__global__ __launch_bounds__(256) void combine_kernel(
    const float* __restrict__ pO, const float* __restrict__ den,
    float* __restrict__ attnbuf)
{
    const int idx = blockIdx.x * 256 + threadIdx.x;
    const int d4 = idx & 7;
    const int q  = (idx >> 3) & (S_LEN - 1);
    const int h  = (idx >> 15) & 3;
    const int c  = idx >> 17;

    const size_t bq = ((size_t)c * NHEAD + h) * S_LEN + q;
    const size_t plane = (size_t)CBATCH * NHEAD * S_LEN;
    float4 acc = {0.f, 0.f, 0.f, 0.f};
    float dsum = 0.f;
    #pragma unroll
    for (int s = 0; s < NS; ++s) {
        const size_t b = (size_t)s * plane + bq;
        float4 a = *(const float4*)&pO[b * HDIM + d4 * 4];
        acc.x += a.x; acc.y += a.y; acc.z += a.z; acc.w += a.w;
        dsum += den[b];
    }
    float inv = 1.0f / dsum;
    float4 o;
    o.x = acc.x * inv;
    o.y = acc.y * inv;
    o.z = acc.z * inv;
    o.w = acc.w * inv;
    *(float4*)&attnbuf[((size_t)c * S_LEN + q) * HID + h * HDIM + d4 * 4] = o;
}

// ---------------------------------------------------------------------------
// Kernel 5: output projection. out = attnbuf @ Wo.T + bo   (all fp32)
// ---------------------------------------------------------------------------
__global__ __launch_bounds__(256) void out_proj_kernel(
    const float* __restrict__ ain, const float* __restrict__ Wo,
    const float* __restrict__ bo, float* __restrict__ out)
{
    __shared__ float xs[64][132];
    __shared__ float wsT[64][68];

    const int tid = threadIdx.x;
    const int mrow0 = blockIdx.x * 64;
    const int n0 = blockIdx.y * 64;

    for (int i = tid; i < 64 * 32; i += 256) {
        int r = i >> 5, c4 = (i & 31) * 4;
        *(float4*)&xs[r][c4] = *(const float4*)&ain[(size_t)(mrow0 + r) * HID + c4];
    }

    float acc[4][4] = {};
    const int tr = tid >> 4;
    const int tc = tid & 15;

    for (int ph = 0; ph < 2; ++ph) {
        __syncthreads();
        for (int i = tid; i < 64 * 16; i += 256) {
            int r = i >> 4, c4 = (i & 15) * 4;
            float4 wv = *(const float4*)&Wo[(size_t)(n0 + r) * HID + ph * 64 + c4];
            wsT[c4 + 0][r] = wv.x;
            wsT[c4 + 1][r] = wv.y;
            wsT[c4 + 2][r] = wv.z;
            wsT[c4 + 3][r] = wv.w;
        }
        __syncthreads();
        #pragma unroll 4
        for (int k4 = 0; k4 < 16; ++k4) {
            float4 xv[4];
            #pragma unroll
            for (int i = 0; i < 4; ++i)
                xv[i] = *(const float4*)&xs[tr * 4 + i][ph * 64 + k4 * 4];
            #pragma unroll
            for (int kk = 0; kk < 4; ++kk) {
                float4 wv = *(const float4*)&wsT[k4 * 4 + kk][tc * 4];
                #pragma unroll
                for (int i = 0; i < 4; ++i) {
                    float xk = ((const float*)&xv[i])[kk];
                    acc[i][0] += xk * wv.x;
                    acc[i][1] += xk * wv.y;
                    acc[i][2] += xk * wv.z;
                    acc[i][3] += xk * wv.w;
                }
            }
        }
    }

    float4 bv4 = *(const float4*)&bo[n0 + tc * 4];
    #pragma unroll
    for (int i = 0; i < 4; ++i) {
        int m = mrow0 + tr * 4 + i;
        float4 o;
        o.x = acc[i][0] + bv4.x;
        o.y = acc[i][1] + bv4.y;
        o.z = acc[i][2] + bv4.z;
        o.w = acc[i][3] + bv4.w;
        *(float4*)&out[(size_t)m * HID + n0 + tc * 4] = o;
    }
}

extern "C" void kernel_launch(void* const* d_in, const int* in_sizes, int n_in,
                              void* d_out, int out_size, void* d_ws, size_t ws_size,
                              hipStream_t stream) {
    const float* x  = (const float*)d_in[0];
    const float* ew = (const float*)d_in[1];
    const float* Wq = (const float*)d_in[2];
    const float* bq = (const float*)d_in[3];
    const float* Wk = (const float*)d_in[4];
    const float* bk = (const float*)d_in[5];
    const float* Wv = (const float*)d_in[6];
    const float* bv = (const float*)d_in[7];
    const float* Wo = (const float*)d_in[8];
    const float* bo = (const float*)d_in[9];
    float* out = (float*)d_out;

    char* ws = (char*)d_ws;
    const size_t QSZ = (size_t)CBATCH * NHEAD * S_LEN * HDIM * sizeof(unsigned short); // 4 MiB
    const size_t PLANE_O = (size_t)CBATCH * NHEAD * S_LEN * HDIM * sizeof(float);      // 8 MiB
    const size_t PLANE_D = (size_t)CBATCH * NHEAD * S_LEN * sizeof(float);             // 256 KiB

    // choose NSPLIT by workspace capacity (deterministic: ws_size fixed per run)
    const size_t need4 = 3 * QSZ + 4 * PLANE_O + 4 * PLANE_D;
    const int ns = (ws_size >= need4) ? 4 : 2;

    unsigned short* Qw  = (unsigned short*)(ws);
    unsigned short* Kw  = (unsigned short*)(ws + QSZ);
    unsigned short* Vtw = (unsigned short*)(ws + 2 * QSZ);
    unsigned short* Vw  = (unsigned short*)(ws + 3 * QSZ);
    float* partO = (float*)(ws + 3 * QSZ);                 // overlaps dead Vw
    float* den   = (float*)(ws + 3 * QSZ + (size_t)ns * PLANE_O);
    float* attnbuf = (float*)(ws);                          // overlaps dead Qw/Kw

    qkv_proj_kernel<<<dim3(256, 2, 3), 256, 0, stream>>>(x, Wq, bq, Wk, bk, Wv, bv, Qw, Kw, Vw);
    vtrans_kernel<<<dim3(S_LEN / 64, CBATCH * NHEAD), 256, 0, stream>>>(Vw, Vtw);
    if (ns == 4) {
        attn_kernel<4><<<dim3(S_LEN / 64, CBATCH, 4), 256, 0, stream>>>(Qw, Kw, Vtw, ew, partO, den);
        combine_kernel<4><<<dim3((CBATCH * S_LEN * HID / 4) / 256), 256, 0, stream>>>(partO, den, attnbuf);
    } else {
        attn_kernel<2><<<dim3(S_LEN / 64, CBATCH, 2), 256, 0, stream>>>(Qw, Kw, Vtw, ew, partO, den);
        combine_kernel<2><<<dim3((CBATCH * S_LEN * HID / 4) / 256), 256, 0, stream>>>(partO, den, attnbuf);
    }
    out_proj_kernel<<<dim3(256, 2), 256, 0, stream>>>(attnbuf, Wo, bo, out);
}

// Round 10
// 217.070 us; speedup vs baseline: 1.4837x; 1.2269x over previous
//
#include <hip/hip_runtime.h>
#include <hip/hip_bf16.h>
#include <cstdint>

#define S_LEN 4096
#define NHEAD 4
#define HDIM 32
#define HID 128
#define CBATCH 4
#define EPSW 1e-8f

typedef __attribute__((ext_vector_type(8))) short short8v;
typedef __attribute__((ext_vector_type(4))) float float4v;

__device__ __forceinline__ unsigned short f2bf(float f) {
    unsigned int u = __float_as_uint(f);
    return (unsigned short)((u + 0x7fffu + ((u >> 16) & 1u)) >> 16);
}

__device__ __forceinline__ float exp2_asm(float x) {
    float r;
    asm("v_exp_f32 %0, %1" : "=v"(r) : "v"(x));
    return r;
}

__device__ __forceinline__ unsigned cvt_pk_bf16(float lo, float hi) {
    unsigned r;
    asm("v_cvt_pk_bf16_f32 %0, %1, %2" : "=v"(r) : "v"(lo), "v"(hi));
    return r;
}

// async global->LDS, 16B per lane; LDS dest = wave-uniform base + lane*16
__device__ __forceinline__ void gload16(const void* g, void* l) {
    __builtin_amdgcn_global_load_lds(
        (const __attribute__((address_space(1))) void*)g,
        (__attribute__((address_space(3))) void*)l,
        16, 0, 0);
}

// ---------------------------------------------------------------------------
// Kernel 1: fused QKV projection.  out = (x @ W.T + b) [* SCALE*log2e for Q]
// ---------------------------------------------------------------------------
__global__ __launch_bounds__(256) void qkv_proj_kernel(
    const float* __restrict__ x,
    const float* __restrict__ Wq, const float* __restrict__ bq,
    const float* __restrict__ Wk, const float* __restrict__ bk,
    const float* __restrict__ Wv, const float* __restrict__ bv,
    unsigned short* __restrict__ Qo, unsigned short* __restrict__ Ko,
    unsigned short* __restrict__ Vo)
{
    __shared__ float xs[64][132];
    __shared__ float wsT[64][68];

    const int tid = threadIdx.x;
    const int mrow0 = blockIdx.x * 64;
    const int n0 = blockIdx.y * 64;
    const int p = blockIdx.z;
    const float* W    = (p == 0) ? Wq : (p == 1) ? Wk : Wv;
    const float* bias = (p == 0) ? bq : (p == 1) ? bk : bv;
    unsigned short* Out = (p == 0) ? Qo : (p == 1) ? Ko : Vo;

    for (int i = tid; i < 64 * 32; i += 256) {
        int r = i >> 5, c4 = (i & 31) * 4;
        *(float4*)&xs[r][c4] = *(const float4*)&x[(size_t)(mrow0 + r) * HID + c4];
    }

    float acc[4][4] = {};
    const int tr = tid >> 4;
    const int tc = tid & 15;

    for (int ph = 0; ph < 2; ++ph) {
        __syncthreads();
        for (int i = tid; i < 64 * 16; i += 256) {
            int r = i >> 4, c4 = (i & 15) * 4;
            float4 wv = *(const float4*)&W[(size_t)(n0 + r) * HID + ph * 64 + c4];
            wsT[c4 + 0][r] = wv.x;
            wsT[c4 + 1][r] = wv.y;
            wsT[c4 + 2][r] = wv.z;
            wsT[c4 + 3][r] = wv.w;
        }
        __syncthreads();
        #pragma unroll 4
        for (int k4 = 0; k4 < 16; ++k4) {
            float4 xv[4];
            #pragma unroll
            for (int i = 0; i < 4; ++i)
                xv[i] = *(const float4*)&xs[tr * 4 + i][ph * 64 + k4 * 4];
            #pragma unroll
            for (int kk = 0; kk < 4; ++kk) {
                float4 wv = *(const float4*)&wsT[k4 * 4 + kk][tc * 4];
                #pragma unroll
                for (int i = 0; i < 4; ++i) {
                    float xk = ((const float*)&xv[i])[kk];
                    acc[i][0] += xk * wv.x;
                    acc[i][1] += xk * wv.y;
                    acc[i][2] += xk * wv.z;
                    acc[i][3] += xk * wv.w;
                }
            }
        }
    }

    // SCALE * log2(e): exp(s*SCALE) == exp2(s * SCALE * log2e)
    const float scale = (p == 0) ? 0.25500544458521289f : 1.0f;
    float4 bv4 = *(const float4*)&bias[n0 + tc * 4];
    const int nbase = n0 + tc * 4;
    const int h = nbase >> 5;
    const int d = nbase & 31;
    #pragma unroll
    for (int i = 0; i < 4; ++i) {
        int m = mrow0 + tr * 4 + i;
        int c = m >> 12, s = m & 4095;
        unsigned short pk[4];
        pk[0] = f2bf((acc[i][0] + bv4.x) * scale);
        pk[1] = f2bf((acc[i][1] + bv4.y) * scale);
        pk[2] = f2bf((acc[i][2] + bv4.z) * scale);
        pk[3] = f2bf((acc[i][3] + bv4.w) * scale);
        *(uint2*)&Out[((size_t)(c * NHEAD + h) * S_LEN + s) * HDIM + d] = *(uint2*)pk;
    }
}

// ---------------------------------------------------------------------------
// Kernel 2: transpose V (C,NH,S,HD) -> Vt (C,NH,HD,S), bf16.  [validated]
// ---------------------------------------------------------------------------
__global__ __launch_bounds__(256) void vtrans_kernel(
    const unsigned short* __restrict__ V, unsigned short* __restrict__ Vt)
{
    __shared__ unsigned short vs[64][40];
    const int tid = threadIdx.x;
    const int chh = blockIdx.y;
    const int s0 = blockIdx.x * 64;
    const size_t base = (size_t)chh * S_LEN * HDIM;
    {
        int r = tid >> 2, ch = (tid & 3) * 8;
        *(uint4*)&vs[r][ch] = *(const uint4*)&V[base + (size_t)(s0 + r) * HDIM + ch];
    }
    __syncthreads();
    {
        int dd = tid >> 3, chs = (tid & 7) * 8;
        unsigned short pk[8];
        #pragma unroll
        for (int j = 0; j < 8; ++j) pk[j] = vs[chs + j][dd];
        *(uint4*)&Vt[(size_t)chh * HDIM * S_LEN + (size_t)dd * S_LEN + s0 + chs] = *(uint4*)pk;
    }
}

// ---------------------------------------------------------------------------
// Kernel 3: attention, split-K, LDS double-buffered via global_load_lds.
// Fragment-order staging (r6 body, math re-audited): per-lane GLOBAL source
// chosen so each LDS region holds exactly the fragment its reader consumes.
// ew staged ONCE per block (was 4x redundant per-wave in r9).
// NOTE: plain __launch_bounds__(256) — (256,4) was the r3/5/6/7 poison (r8).
// ---------------------------------------------------------------------------
template<int NS>
__global__ __launch_bounds__(256) void attn_kernel(
    const unsigned short* __restrict__ Q, const unsigned short* __restrict__ K,
    const unsigned short* __restrict__ Vt, const float* __restrict__ ew,
    float* __restrict__ partO, float* __restrict__ den)
{
    const int KCHUNK = S_LEN / NS;
    const int NIT = KCHUNK / 32;

    __shared__ float ew_lds[2][1024];            // 2 x 4KB: 4 regions x 64 lanes x 4 floats
    __shared__ unsigned short k_lds[2][4096];    // 2 x 8KB: [wave][kf0|kf1][lane*8]
    __shared__ unsigned short v_lds[2][4096];    // 2 x 8KB: [wave][d 0..31][32 keys]

    const int tid = threadIdx.x;
    const int w = tid >> 6;          // head
    const int lane = tid & 63;
    const int li = lane & 15;
    const int g = lane >> 4;
    const int c = blockIdx.y;
    const int qbase = blockIdx.x * 32;
    const int split = blockIdx.z;
    const int kb0 = split * KCHUNK;
    const int chh = c * NHEAD + w;

    const size_t hb = (size_t)chh * S_LEN * HDIM;
    const unsigned short* Qh = Q + hb;
    const unsigned short* Kh = K + hb;
    const unsigned short* Vth = Vt + hb;
    const float* ewc = ew + (size_t)c * S_LEN * S_LEN;

    short8v qf0 = *(const short8v*)&Qh[(size_t)(qbase + li) * HDIM + g * 8];
    short8v qf1 = *(const short8v*)&Qh[(size_t)(qbase + 16 + li) * HDIM + g * 8];

    // ---- staging source pointers (per lane, fragment-order) ----
    // ew region w: rows qbase + (w>>1)*16 + li, cols kb + (w&1)*16 + g*4
    const float* ew_src = ewc + (size_t)(qbase + (w >> 1) * 16 + li) * S_LEN + kb0
                        + (w & 1) * 16 + g * 4;
    // K: lane stages its own fragment (round-1 kp address)
    const unsigned short* k_src = Kh + (size_t)(kb0 + li) * HDIM + g * 8;
    // V row-major: lane covers (d = lane>>2, keys (lane&3)*8..+7)
    const unsigned short* v_src = Vth + (size_t)(lane >> 2) * S_LEN + kb0 + (lane & 3) * 8;

    float4v o00 = {}, o01 = {}, o10 = {}, o11 = {};
    float den0 = 0.f, den1 = 0.f;
    const float4v zero4 = {0.f, 0.f, 0.f, 0.f};

    #define STAGE(b) do { \
        gload16(ew_src,              &ew_lds[b][w * 256]); \
        gload16(k_src,               &k_lds[b][w * 1024]); \
        gload16(k_src + 16 * HDIM,   &k_lds[b][w * 1024 + 512]); \
        gload16(v_src,               &v_lds[b][w * 1024]); \
        gload16(v_src + 16 * S_LEN,  &v_lds[b][w * 1024 + 512]); \
    } while (0)

    STAGE(0);
    ew_src += 32; k_src += 32 * HDIM; v_src += 32;
    __syncthreads();

    int cur = 0;
    for (int it = 0; it < NIT; ++it) {
        if (it + 1 < NIT) {
            STAGE(cur ^ 1);
            ew_src += 32; k_src += 32 * HDIM; v_src += 32;
        }

        const unsigned short* kw = &k_lds[cur][w * 1024];
        const unsigned short* vw = &v_lds[cur][w * 1024];
        const float* eb = ew_lds[cur];

        short8v kf0 = *(const short8v*)&kw[lane * 8];
        short8v kf1 = *(const short8v*)&kw[512 + lane * 8];

        union { short8v v; uint2 u2[2]; } v0, v1;
        v0.u2[0] = *(const uint2*)&vw[li * 32 + g * 4];
        v0.u2[1] = *(const uint2*)&vw[li * 32 + 16 + g * 4];
        v1.u2[0] = *(const uint2*)&vw[512 + li * 32 + g * 4];
        v1.u2[1] = *(const uint2*)&vw[512 + li * 32 + 16 + g * 4];

        float4 e00 = *(const float4*)&eb[lane * 4];
        float4 e01 = *(const float4*)&eb[256 + lane * 4];
        float4 e10 = *(const float4*)&eb[512 + lane * 4];
        float4 e11 = *(const float4*)&eb[768 + lane * 4];

        float4v s0 = __builtin_amdgcn_mfma_f32_16x16x32_bf16(kf0, qf0, zero4, 0, 0, 0);
        float4v s1 = __builtin_amdgcn_mfma_f32_16x16x32_bf16(kf1, qf0, zero4, 0, 0, 0);
        float4v s2 = __builtin_amdgcn_mfma_f32_16x16x32_bf16(kf0, qf1, zero4, 0, 0, 0);
        float4v s3 = __builtin_amdgcn_mfma_f32_16x16x32_bf16(kf1, qf1, zero4, 0, 0, 0);

        float p0 = fmaxf(e00.x, EPSW) * exp2_asm(s0[0]);
        float p1 = fmaxf(e00.y, EPSW) * exp2_asm(s0[1]);
        float p2 = fmaxf(e00.z, EPSW) * exp2_asm(s0[2]);
        float p3 = fmaxf(e00.w, EPSW) * exp2_asm(s0[3]);
        float p4 = fmaxf(e01.x, EPSW) * exp2_asm(s1[0]);
        float p5 = fmaxf(e01.y, EPSW) * exp2_asm(s1[1]);
        float p6 = fmaxf(e01.z, EPSW) * exp2_asm(s1[2]);
        float p7 = fmaxf(e01.w, EPSW) * exp2_asm(s1[3]);
        union { short8v v; unsigned u[4]; } pu0;
        pu0.u[0] = cvt_pk_bf16(p0, p1);
        pu0.u[1] = cvt_pk_bf16(p2, p3);
        pu0.u[2] = cvt_pk_bf16(p4, p5);
        pu0.u[3] = cvt_pk_bf16(p6, p7);
        den0 += ((p0 + p1) + (p2 + p3)) + ((p4 + p5) + (p6 + p7));
        o00 = __builtin_amdgcn_mfma_f32_16x16x32_bf16(v0.v, pu0.v, o00, 0, 0, 0);
        o01 = __builtin_amdgcn_mfma_f32_16x16x32_bf16(v1.v, pu0.v, o01, 0, 0, 0);

        float r0 = fmaxf(e10.x, EPSW) * exp2_asm(s2[0]);
        float r1 = fmaxf(e10.y, EPSW) * exp2_asm(s2[1]);
        float r2 = fmaxf(e10.z, EPSW) * exp2_asm(s2[2]);
        float r3 = fmaxf(e10.w, EPSW) * exp2_asm(s2[3]);
        float r4 = fmaxf(e11.x, EPSW) * exp2_asm(s3[0]);
        float r5 = fmaxf(e11.y, EPSW) * exp2_asm(s3[1]);
        float r6 = fmaxf(e11.z, EPSW) * exp2_asm(s3[2]);
        float r7 = fmaxf(e11.w, EPSW) * exp2_asm(s3[3]);
        union { short8v v; unsigned u[4]; } pu1;
        pu1.u[0] = cvt_pk_bf16(r0, r1);
        pu1.u[1] = cvt_pk_bf16(r2, r3);
        pu1.u[2] = cvt_pk_bf16(r4, r5);
        pu1.u[3] = cvt_pk_bf16(r6, r7);
        den1 += ((r0 + r1) + (r2 + r3)) + ((r4 + r5) + (r6 + r7));
        o10 = __builtin_amdgcn_mfma_f32_16x16x32_bf16(v0.v, pu1.v, o10, 0, 0, 0);
        o11 = __builtin_amdgcn_mfma_f32_16x16x32_bf16(v1.v, pu1.v, o11, 0, 0, 0);

        __syncthreads();
        cur ^= 1;
    }
    #undef STAGE

    den0 += __shfl_xor(den0, 16, 64);
    den0 += __shfl_xor(den0, 32, 64);
    den1 += __shfl_xor(den1, 16, 64);
    den1 += __shfl_xor(den1, 32, 64);

    const size_t pbase = (((size_t)split * CBATCH + c) * NHEAD + w) * S_LEN + qbase;
    {
        const size_t pb = pbase + li;
        float4 o;
        o.x = o00[0]; o.y = o00[1]; o.z = o00[2]; o.w = o00[3];
        *(float4*)&partO[pb * HDIM + 0 * 16 + g * 4] = o;
        o.x = o01[0]; o.y = o01[1]; o.z = o01[2]; o.w = o01[3];
        *(float4*)&partO[pb * HDIM + 1 * 16 + g * 4] = o;
        if (g == 0) den[pb] = den0;
    }
    {
        const size_t pb = pbase + 16 + li;
        float4 o;
        o.x = o10[0]; o.y = o10[1]; o.z = o10[2]; o.w = o10[3];
        *(float4*)&partO[pb * HDIM + 0 * 16 + g * 4] = o;
        o.x = o11[0]; o.y = o11[1]; o.z = o11[2]; o.w = o11[3];
        *(float4*)&partO[pb * HDIM + 1 * 16 + g * 4] = o;
        if (g == 0) den[pb] = den1;
    }
}

// ---------------------------------------------------------------------------
// Kernel 4: combine NS splits -> normalized attention output (C,S,HID) fp32.
// ---------------------------------------------------------------------------
template<int NS>
__global__ __launch_bounds__(256) void combine_kernel(
    const float* __restrict__ pO, const float* __restrict__ den,
    float* __restrict__ attnbuf)
{
    const int idx = blockIdx.x * 256 + threadIdx.x;
    const int d4 = idx & 7;
    const int q  = (idx >> 3) & (S_LEN - 1);
    const int h  = (idx >> 15) & 3;
    const int c  = idx >> 17;

    const size_t bq = ((size_t)c * NHEAD + h) * S_LEN + q;
    const size_t plane = (size_t)CBATCH * NHEAD * S_LEN;
    float4 acc = {0.f, 0.f, 0.f, 0.f};
    float dsum = 0.f;
    #pragma unroll
    for (int s = 0; s < NS; ++s) {
        const size_t b = (size_t)s * plane + bq;
        float4 a = *(const float4*)&pO[b * HDIM + d4 * 4];
        acc.x += a.x; acc.y += a.y; acc.z += a.z; acc.w += a.w;
        dsum += den[b];
    }
    float inv = 1.0f / dsum;
    float4 o;
    o.x = acc.x * inv;
    o.y = acc.y * inv;
    o.z = acc.z * inv;
    o.w = acc.w * inv;
    *(float4*)&attnbuf[((size_t)c * S_LEN + q) * HID + h * HDIM + d4 * 4] = o;
}

// ---------------------------------------------------------------------------
// Kernel 5: output projection. out = attnbuf @ Wo.T + bo   (all fp32)
// ---------------------------------------------------------------------------
__global__ __launch_bounds__(256) void out_proj_kernel(
    const float* __restrict__ ain, const float* __restrict__ Wo,
    const float* __restrict__ bo, float* __restrict__ out)
{
    __shared__ float xs[64][132];
    __shared__ float wsT[64][68];

    const int tid = threadIdx.x;
    const int mrow0 = blockIdx.x * 64;
    const int n0 = blockIdx.y * 64;

    for (int i = tid; i < 64 * 32; i += 256) {
        int r = i >> 5, c4 = (i & 31) * 4;
        *(float4*)&xs[r][c4] = *(const float4*)&ain[(size_t)(mrow0 + r) * HID + c4];
    }

    float acc[4][4] = {};
    const int tr = tid >> 4;
    const int tc = tid & 15;

    for (int ph = 0; ph < 2; ++ph) {
        __syncthreads();
        for (int i = tid; i < 64 * 16; i += 256) {
            int r = i >> 4, c4 = (i & 15) * 4;
            float4 wv = *(const float4*)&Wo[(size_t)(n0 + r) * HID + ph * 64 + c4];
            wsT[c4 + 0][r] = wv.x;
            wsT[c4 + 1][r] = wv.y;
            wsT[c4 + 2][r] = wv.z;
            wsT[c4 + 3][r] = wv.w;
        }
        __syncthreads();
        #pragma unroll 4
        for (int k4 = 0; k4 < 16; ++k4) {
            float4 xv[4];
            #pragma unroll
            for (int i = 0; i < 4; ++i)
                xv[i] = *(const float4*)&xs[tr * 4 + i][ph * 64 + k4 * 4];
            #pragma unroll
            for (int kk = 0; kk < 4; ++kk) {
                float4 wv = *(const float4*)&wsT[k4 * 4 + kk][tc * 4];
                #pragma unroll
                for (int i = 0; i < 4; ++i) {
                    float xk = ((const float*)&xv[i])[kk];
                    acc[i][0] += xk * wv.x;
                    acc[i][1] += xk * wv.y;
                    acc[i][2] += xk * wv.z;
                    acc[i][3] += xk * wv.w;
                }
            }
        }
    }

    float4 bv4 = *(const float4*)&bo[n0 + tc * 4];
    #pragma unroll
    for (int i = 0; i < 4; ++i) {
        int m = mrow0 + tr * 4 + i;
        float4 o;
        o.x = acc[i][0] + bv4.x;
        o.y = acc[i][1] + bv4.y;
        o.z = acc[i][2] + bv4.z;
        o.w = acc[i][3] + bv4.w;
        *(float4*)&out[(size_t)m * HID + n0 + tc * 4] = o;
    }
}

extern "C" void kernel_launch(void* const* d_in, const int* in_sizes, int n_in,
                              void* d_out, int out_size, void* d_ws, size_t ws_size,
                              hipStream_t stream) {
    const float* x  = (const float*)d_in[0];
    const float* ew = (const float*)d_in[1];
    const float* Wq = (const float*)d_in[2];
    const float* bq = (const float*)d_in[3];
    const float* Wk = (const float*)d_in[4];
    const float* bk = (const float*)d_in[5];
    const float* Wv = (const float*)d_in[6];
    const float* bv = (const float*)d_in[7];
    const float* Wo = (const float*)d_in[8];
    const float* bo = (const float*)d_in[9];
    float* out = (float*)d_out;

    char* ws = (char*)d_ws;
    const size_t QSZ = (size_t)CBATCH * NHEAD * S_LEN * HDIM * sizeof(unsigned short); // 4 MiB
    const size_t PLANE_O = (size_t)CBATCH * NHEAD * S_LEN * HDIM * sizeof(float);      // 8 MiB
    const size_t PLANE_D = (size_t)CBATCH * NHEAD * S_LEN * sizeof(float);             // 256 KiB

    // choose NSPLIT by workspace capacity (deterministic: ws_size fixed per run)
    const size_t need4 = 3 * QSZ + 4 * PLANE_O + 4 * PLANE_D;
    const int ns = (ws_size >= need4) ? 4 : 2;

    unsigned short* Qw  = (unsigned short*)(ws);
    unsigned short* Kw  = (unsigned short*)(ws + QSZ);
    unsigned short* Vtw = (unsigned short*)(ws + 2 * QSZ);
    unsigned short* Vw  = (unsigned short*)(ws + 3 * QSZ);
    float* partO = (float*)(ws + 3 * QSZ);                 // overlaps dead Vw
    float* den   = (float*)(ws + 3 * QSZ + (size_t)ns * PLANE_O);
    float* attnbuf = (float*)(ws);                          // overlaps dead Qw/Kw

    qkv_proj_kernel<<<dim3(256, 2, 3), 256, 0, stream>>>(x, Wq, bq, Wk, bk, Wv, bv, Qw, Kw, Vw);
    vtrans_kernel<<<dim3(S_LEN / 64, CBATCH * NHEAD), 256, 0, stream>>>(Vw, Vtw);
    if (ns == 4) {
        attn_kernel<4><<<dim3(S_LEN / 32, CBATCH, 4), 256, 0, stream>>>(Qw, Kw, Vtw, ew, partO, den);
        combine_kernel<4><<<dim3((CBATCH * S_LEN * HID / 4) / 256), 256, 0, stream>>>(partO, den, attnbuf);
    } else {
        attn_kernel<2><<<dim3(S_LEN / 32, CBATCH, 2), 256, 0, stream>>>(Qw, Kw, Vtw, ew, partO, den);
        combine_kernel<2><<<dim3((CBATCH * S_LEN * HID / 4) / 256), 256, 0, stream>>>(partO, den, attnbuf);
    }
    out_proj_kernel<<<dim3(256, 2), 256, 0, stream>>>(attnbuf, Wo, bo, out);
}

// Round 11
// 206.383 us; speedup vs baseline: 1.5605x; 1.0518x over previous
//
#include <hip/hip_runtime.h>
#include <hip/hip_bf16.h>
#include <cstdint>

#define S_LEN 4096
#define NHEAD 4
#define HDIM 32
#define HID 128
#define CBATCH 4
#define EPSW 1e-8f
#define NCHUNKS (S_LEN / 32)

typedef __attribute__((ext_vector_type(8))) short short8v;
typedef __attribute__((ext_vector_type(4))) float float4v;

__device__ __forceinline__ unsigned short f2bf(float f) {
    unsigned int u = __float_as_uint(f);
    return (unsigned short)((u + 0x7fffu + ((u >> 16) & 1u)) >> 16);
}

__device__ __forceinline__ float exp2_asm(float x) {
    float r;
    asm("v_exp_f32 %0, %1" : "=v"(r) : "v"(x));
    return r;
}

__device__ __forceinline__ unsigned cvt_pk_bf16(float lo, float hi) {
    unsigned r;
    asm("v_cvt_pk_bf16_f32 %0, %1, %2" : "=v"(r) : "v"(lo), "v"(hi));
    return r;
}

// async global->LDS, 16B per lane; LDS dest = wave-uniform base + lane*16
__device__ __forceinline__ void gload16(const void* g, void* l) {
    __builtin_amdgcn_global_load_lds(
        (const __attribute__((address_space(1))) void*)g,
        (__attribute__((address_space(3))) void*)l,
        16, 0, 0);
}

// ---------------------------------------------------------------------------
// Kernel 1: fused QKV projection.  out = (x @ W.T + b) [* SCALE*log2e for Q]
// ---------------------------------------------------------------------------
__global__ __launch_bounds__(256) void qkv_proj_kernel(
    const float* __restrict__ x,
    const float* __restrict__ Wq, const float* __restrict__ bq,
    const float* __restrict__ Wk, const float* __restrict__ bk,
    const float* __restrict__ Wv, const float* __restrict__ bv,
    unsigned short* __restrict__ Qo, unsigned short* __restrict__ Ko,
    unsigned short* __restrict__ Vo)
{
    __shared__ float xs[64][132];
    __shared__ float wsT[64][68];

    const int tid = threadIdx.x;
    const int mrow0 = blockIdx.x * 64;
    const int n0 = blockIdx.y * 64;
    const int p = blockIdx.z;
    const float* W    = (p == 0) ? Wq : (p == 1) ? Wk : Wv;
    const float* bias = (p == 0) ? bq : (p == 1) ? bk : bv;
    unsigned short* Out = (p == 0) ? Qo : (p == 1) ? Ko : Vo;

    for (int i = tid; i < 64 * 32; i += 256) {
        int r = i >> 5, c4 = (i & 31) * 4;
        *(float4*)&xs[r][c4] = *(const float4*)&x[(size_t)(mrow0 + r) * HID + c4];
    }

    float acc[4][4] = {};
    const int tr = tid >> 4;
    const int tc = tid & 15;

    for (int ph = 0; ph < 2; ++ph) {
        __syncthreads();
        for (int i = tid; i < 64 * 16; i += 256) {
            int r = i >> 4, c4 = (i & 15) * 4;
            float4 wv = *(const float4*)&W[(size_t)(n0 + r) * HID + ph * 64 + c4];
            wsT[c4 + 0][r] = wv.x;
            wsT[c4 + 1][r] = wv.y;
            wsT[c4 + 2][r] = wv.z;
            wsT[c4 + 3][r] = wv.w;
        }
        __syncthreads();
        #pragma unroll 4
        for (int k4 = 0; k4 < 16; ++k4) {
            float4 xv[4];
            #pragma unroll
            for (int i = 0; i < 4; ++i)
                xv[i] = *(const float4*)&xs[tr * 4 + i][ph * 64 + k4 * 4];
            #pragma unroll
            for (int kk = 0; kk < 4; ++kk) {
                float4 wv = *(const float4*)&wsT[k4 * 4 + kk][tc * 4];
                #pragma unroll
                for (int i = 0; i < 4; ++i) {
                    float xk = ((const float*)&xv[i])[kk];
                    acc[i][0] += xk * wv.x;
                    acc[i][1] += xk * wv.y;
                    acc[i][2] += xk * wv.z;
                    acc[i][3] += xk * wv.w;
                }
            }
        }
    }

    // SCALE * log2(e): exp(s*SCALE) == exp2(s * SCALE * log2e)
    const float scale = (p == 0) ? 0.25500544458521289f : 1.0f;
    float4 bv4 = *(const float4*)&bias[n0 + tc * 4];
    const int nbase = n0 + tc * 4;
    const int h = nbase >> 5;
    const int d = nbase & 31;
    #pragma unroll
    for (int i = 0; i < 4; ++i) {
        int m = mrow0 + tr * 4 + i;
        int c = m >> 12, s = m & 4095;
        unsigned short pk[4];
        pk[0] = f2bf((acc[i][0] + bv4.x) * scale);
        pk[1] = f2bf((acc[i][1] + bv4.y) * scale);
        pk[2] = f2bf((acc[i][2] + bv4.z) * scale);
        pk[3] = f2bf((acc[i][3] + bv4.w) * scale);
        *(uint2*)&Out[((size_t)(c * NHEAD + h) * S_LEN + s) * HDIM + d] = *(uint2*)pk;
    }
}

// ---------------------------------------------------------------------------
// Kernel 2: repack V (C,NH,S,HD) -> Vt2: exact PV A-fragment order.
// Vt2[((chh*2+db)*NCHUNKS + chunk)*512 + lane*8 + j] =
//    V[chh][key = chunk*32 + pi(g,j)][d = db*16 + li]
// where pi(g,j) = (j<4) ? 4g+j : 16+4g+(j-4)  — the SAME k-permutation the
// P-fragment uses, so the PV contraction is consistent.
// ---------------------------------------------------------------------------
__global__ __launch_bounds__(256) void vtrans_kernel(
    const unsigned short* __restrict__ V, unsigned short* __restrict__ Vt2)
{
    __shared__ unsigned short vs[64][40];
    const int tid = threadIdx.x;
    const int chh = blockIdx.y;
    const int s0 = blockIdx.x * 64;
    const size_t base = (size_t)chh * S_LEN * HDIM;
    {
        int r = tid >> 2, ch = (tid & 3) * 8;
        *(uint4*)&vs[r][ch] = *(const uint4*)&V[base + (size_t)(s0 + r) * HDIM + ch];
    }
    __syncthreads();
    {
        const int lchunk = tid >> 7;         // 0..1
        const int db = (tid >> 6) & 1;       // 0..1
        const int l = tid & 63;
        const int li = l & 15;
        const int g = l >> 4;
        unsigned short pk[8];
        #pragma unroll
        for (int j = 0; j < 8; ++j) {
            int key = lchunk * 32 + ((j < 4) ? (4 * g + j) : (16 + 4 * g + (j - 4)));
            pk[j] = vs[key][db * 16 + li];
        }
        size_t chunk = (size_t)(s0 >> 5) + lchunk;
        *(uint4*)&Vt2[(((size_t)chh * 2 + db) * NCHUNKS + chunk) * 512 + l * 8] = *(uint4*)pk;
    }
}

// ---------------------------------------------------------------------------
// Kernel 3: attention, split-K, LDS double-buffered via global_load_lds.
// Fragment-order staging for ew, K AND V (V via Vt2 repack) — all LDS reads
// are lane-contiguous b128, conflict-free.
// NOTE: plain __launch_bounds__(256) — (256,4) was the r3/5/6/7 poison (r8).
// ---------------------------------------------------------------------------
template<int NS>
__global__ __launch_bounds__(256) void attn_kernel(
    const unsigned short* __restrict__ Q, const unsigned short* __restrict__ K,
    const unsigned short* __restrict__ Vt2, const float* __restrict__ ew,
    float* __restrict__ partO, float* __restrict__ den)
{
    const int KCHUNK = S_LEN / NS;
    const int NIT = KCHUNK / 32;

    __shared__ float ew_lds[2][1024];            // 2 x 4KB: 4 regions x 64 lanes x 4 floats
    __shared__ unsigned short k_lds[2][4096];    // 2 x 8KB: [wave][kf0|kf1][lane*8]
    __shared__ unsigned short v_lds[2][4096];    // 2 x 8KB: [wave][db0|db1][lane*8]

    const int tid = threadIdx.x;
    const int w = tid >> 6;          // head
    const int lane = tid & 63;
    const int li = lane & 15;
    const int g = lane >> 4;
    const int c = blockIdx.y;
    const int qbase = blockIdx.x * 32;
    const int split = blockIdx.z;
    const int kb0 = split * KCHUNK;
    const int chh = c * NHEAD + w;

    const size_t hb = (size_t)chh * S_LEN * HDIM;
    const unsigned short* Qh = Q + hb;
    const unsigned short* Kh = K + hb;
    const float* ewc = ew + (size_t)c * S_LEN * S_LEN;

    short8v qf0 = *(const short8v*)&Qh[(size_t)(qbase + li) * HDIM + g * 8];
    short8v qf1 = *(const short8v*)&Qh[(size_t)(qbase + 16 + li) * HDIM + g * 8];

    // ---- staging source pointers (per lane, fragment-order) ----
    // ew region w: rows qbase + (w>>1)*16 + li, cols kb + (w&1)*16 + g*4
    const float* ew_src = ewc + (size_t)(qbase + (w >> 1) * 16 + li) * S_LEN + kb0
                        + (w & 1) * 16 + g * 4;
    // K: lane stages its own fragment (round-1 kp address)
    const unsigned short* k_src = Kh + (size_t)(kb0 + li) * HDIM + g * 8;
    // V: lane stages its own 16B fragment from Vt2 (contiguous per chunk)
    const unsigned short* v_src0 = Vt2 + (((size_t)chh * 2 + 0) * NCHUNKS + (kb0 >> 5)) * 512 + lane * 8;
    const unsigned short* v_src1 = Vt2 + (((size_t)chh * 2 + 1) * NCHUNKS + (kb0 >> 5)) * 512 + lane * 8;

    float4v o00 = {}, o01 = {}, o10 = {}, o11 = {};
    float den0 = 0.f, den1 = 0.f;
    const float4v zero4 = {0.f, 0.f, 0.f, 0.f};

    #define STAGE(b) do { \
        gload16(ew_src,              &ew_lds[b][w * 256]); \
        gload16(k_src,               &k_lds[b][w * 1024]); \
        gload16(k_src + 16 * HDIM,   &k_lds[b][w * 1024 + 512]); \
        gload16(v_src0,              &v_lds[b][w * 1024]); \
        gload16(v_src1,              &v_lds[b][w * 1024 + 512]); \
    } while (0)

    STAGE(0);
    ew_src += 32; k_src += 32 * HDIM; v_src0 += 512; v_src1 += 512;
    __syncthreads();

    int cur = 0;
    for (int it = 0; it < NIT; ++it) {
        if (it + 1 < NIT) {
            STAGE(cur ^ 1);
            ew_src += 32; k_src += 32 * HDIM; v_src0 += 512; v_src1 += 512;
        }

        const unsigned short* kw = &k_lds[cur][w * 1024];
        const unsigned short* vw = &v_lds[cur][w * 1024];
        const float* eb = ew_lds[cur];

        short8v kf0 = *(const short8v*)&kw[lane * 8];
        short8v kf1 = *(const short8v*)&kw[512 + lane * 8];

        short8v vf0 = *(const short8v*)&vw[lane * 8];
        short8v vf1 = *(const short8v*)&vw[512 + lane * 8];

        float4 e00 = *(const float4*)&eb[lane * 4];
        float4 e01 = *(const float4*)&eb[256 + lane * 4];
        float4 e10 = *(const float4*)&eb[512 + lane * 4];
        float4 e11 = *(const float4*)&eb[768 + lane * 4];

        float4v s0 = __builtin_amdgcn_mfma_f32_16x16x32_bf16(kf0, qf0, zero4, 0, 0, 0);
        float4v s1 = __builtin_amdgcn_mfma_f32_16x16x32_bf16(kf1, qf0, zero4, 0, 0, 0);
        float4v s2 = __builtin_amdgcn_mfma_f32_16x16x32_bf16(kf0, qf1, zero4, 0, 0, 0);
        float4v s3 = __builtin_amdgcn_mfma_f32_16x16x32_bf16(kf1, qf1, zero4, 0, 0, 0);

        float p0 = fmaxf(e00.x, EPSW) * exp2_asm(s0[0]);
        float p1 = fmaxf(e00.y, EPSW) * exp2_asm(s0[1]);
        float p2 = fmaxf(e00.z, EPSW) * exp2_asm(s0[2]);
        float p3 = fmaxf(e00.w, EPSW) * exp2_asm(s0[3]);
        float p4 = fmaxf(e01.x, EPSW) * exp2_asm(s1[0]);
        float p5 = fmaxf(e01.y, EPSW) * exp2_asm(s1[1]);
        float p6 = fmaxf(e01.z, EPSW) * exp2_asm(s1[2]);
        float p7 = fmaxf(e01.w, EPSW) * exp2_asm(s1[3]);
        union { short8v v; unsigned u[4]; } pu0;
        pu0.u[0] = cvt_pk_bf16(p0, p1);
        pu0.u[1] = cvt_pk_bf16(p2, p3);
        pu0.u[2] = cvt_pk_bf16(p4, p5);
        pu0.u[3] = cvt_pk_bf16(p6, p7);
        den0 += ((p0 + p1) + (p2 + p3)) + ((p4 + p5) + (p6 + p7));
        o00 = __builtin_amdgcn_mfma_f32_16x16x32_bf16(vf0, pu0.v, o00, 0, 0, 0);
        o01 = __builtin_amdgcn_mfma_f32_16x16x32_bf16(vf1, pu0.v, o01, 0, 0, 0);

        float r0 = fmaxf(e10.x, EPSW) * exp2_asm(s2[0]);
        float r1 = fmaxf(e10.y, EPSW) * exp2_asm(s2[1]);
        float r2 = fmaxf(e10.z, EPSW) * exp2_asm(s2[2]);
        float r3 = fmaxf(e10.w, EPSW) * exp2_asm(s2[3]);
        float r4 = fmaxf(e11.x, EPSW) * exp2_asm(s3[0]);
        float r5 = fmaxf(e11.y, EPSW) * exp2_asm(s3[1]);
        float r6 = fmaxf(e11.z, EPSW) * exp2_asm(s3[2]);
        float r7 = fmaxf(e11.w, EPSW) * exp2_asm(s3[3]);
        union { short8v v; unsigned u[4]; } pu1;
        pu1.u[0] = cvt_pk_bf16(r0, r1);
        pu1.u[1] = cvt_pk_bf16(r2, r3);
        pu1.u[2] = cvt_pk_bf16(r4, r5);
        pu1.u[3] = cvt_pk_bf16(r6, r7);
        den1 += ((r0 + r1) + (r2 + r3)) + ((r4 + r5) + (r6 + r7));
        o10 = __builtin_amdgcn_mfma_f32_16x16x32_bf16(vf0, pu1.v, o10, 0, 0, 0);
        o11 = __builtin_amdgcn_mfma_f32_16x16x32_bf16(vf1, pu1.v, o11, 0, 0, 0);

        __syncthreads();
        cur ^= 1;
    }
    #undef STAGE

    den0 += __shfl_xor(den0, 16, 64);
    den0 += __shfl_xor(den0, 32, 64);
    den1 += __shfl_xor(den1, 16, 64);
    den1 += __shfl_xor(den1, 32, 64);

    const size_t pbase = (((size_t)split * CBATCH + c) * NHEAD + w) * S_LEN + qbase;
    {
        const size_t pb = pbase + li;
        float4 o;
        o.x = o00[0]; o.y = o00[1]; o.z = o00[2]; o.w = o00[3];
        *(float4*)&partO[pb * HDIM + 0 * 16 + g * 4] = o;
        o.x = o01[0]; o.y = o01[1]; o.z = o01[2]; o.w = o01[3];
        *(float4*)&partO[pb * HDIM + 1 * 16 + g * 4] = o;
        if (g == 0) den[pb] = den0;
    }
    {
        const size_t pb = pbase + 16 + li;
        float4 o;
        o.x = o10[0]; o.y = o10[1]; o.z = o10[2]; o.w = o10[3];
        *(float4*)&partO[pb * HDIM + 0 * 16 + g * 4] = o;
        o.x = o11[0]; o.y = o11[1]; o.z = o11[2]; o.w = o11[3];
        *(float4*)&partO[pb * HDIM + 1 * 16 + g * 4] = o;
        if (g == 0) den[pb] = den1;
    }
}

// ---------------------------------------------------------------------------
// Kernel 4: combine NS splits -> normalized attention output (C,S,HID) fp32.
// ---------------------------------------------------------------------------
template<int NS>
__global__ __launch_bounds__(256) void combine_kernel(
    const float* __restrict__ pO, const float* __restrict__ den,
    float* __restrict__ attnbuf)
{
    const int idx = blockIdx.x * 256 + threadIdx.x;
    const int d4 = idx & 7;
    const int q  = (idx >> 3) & (S_LEN - 1);
    const int h  = (idx >> 15) & 3;
    const int c  = idx >> 17;

    const size_t bq = ((size_t)c * NHEAD + h) * S_LEN + q;
    const size_t plane = (size_t)CBATCH * NHEAD * S_LEN;
    float4 acc = {0.f, 0.f, 0.f, 0.f};
    float dsum = 0.f;
    #pragma unroll
    for (int s = 0; s < NS; ++s) {
        const size_t b = (size_t)s * plane + bq;
        float4 a = *(const float4*)&pO[b * HDIM + d4 * 4];
        acc.x += a.x; acc.y += a.y; acc.z += a.z; acc.w += a.w;
        dsum += den[b];
    }
    float inv = 1.0f / dsum;
    float4 o;
    o.x = acc.x * inv;
    o.y = acc.y * inv;
    o.z = acc.z * inv;
    o.w = acc.w * inv;
    *(float4*)&attnbuf[((size_t)c * S_LEN + q) * HID + h * HDIM + d4 * 4] = o;
}

// ---------------------------------------------------------------------------
// Kernel 5: output projection. out = attnbuf @ Wo.T + bo   (all fp32)
// ---------------------------------------------------------------------------
__global__ __launch_bounds__(256) void out_proj_kernel(
    const float* __restrict__ ain, const float* __restrict__ Wo,
    const float* __restrict__ bo, float* __restrict__ out)
{
    __shared__ float xs[64][132];
    __shared__ float wsT[64][68];

    const int tid = threadIdx.x;
    const int mrow0 = blockIdx.x * 64;
    const int n0 = blockIdx.y * 64;

    for (int i = tid; i < 64 * 32; i += 256) {
        int r = i >> 5, c4 = (i & 31) * 4;
        *(float4*)&xs[r][c4] = *(const float4*)&ain[(size_t)(mrow0 + r) * HID + c4];
    }

    float acc[4][4] = {};
    const int tr = tid >> 4;
    const int tc = tid & 15;

    for (int ph = 0; ph < 2; ++ph) {
        __syncthreads();
        for (int i = tid; i < 64 * 16; i += 256) {
            int r = i >> 4, c4 = (i & 15) * 4;
            float4 wv = *(const float4*)&Wo[(size_t)(n0 + r) * HID + ph * 64 + c4];
            wsT[c4 + 0][r] = wv.x;
            wsT[c4 + 1][r] = wv.y;
            wsT[c4 + 2][r] = wv.z;
            wsT[c4 + 3][r] = wv.w;
        }
        __syncthreads();
        #pragma unroll 4
        for (int k4 = 0; k4 < 16; ++k4) {
            float4 xv[4];
            #pragma unroll
            for (int i = 0; i < 4; ++i)
                xv[i] = *(const float4*)&xs[tr * 4 + i][ph * 64 + k4 * 4];
            #pragma unroll
            for (int kk = 0; kk < 4; ++kk) {
                float4 wv = *(const float4*)&wsT[k4 * 4 + kk][tc * 4];
                #pragma unroll
                for (int i = 0; i < 4; ++i) {
                    float xk = ((const float*)&xv[i])[kk];
                    acc[i][0] += xk * wv.x;
                    acc[i][1] += xk * wv.y;
                    acc[i][2] += xk * wv.z;
                    acc[i][3] += xk * wv.w;
                }
            }
        }
    }

    float4 bv4 = *(const float4*)&bo[n0 + tc * 4];
    #pragma unroll
    for (int i = 0; i < 4; ++i) {
        int m = mrow0 + tr * 4 + i;
        float4 o;
        o.x = acc[i][0] + bv4.x;
        o.y = acc[i][1] + bv4.y;
        o.z = acc[i][2] + bv4.z;
        o.w = acc[i][3] + bv4.w;
        *(float4*)&out[(size_t)m * HID + n0 + tc * 4] = o;
    }
}

extern "C" void kernel_launch(void* const* d_in, const int* in_sizes, int n_in,
                              void* d_out, int out_size, void* d_ws, size_t ws_size,
                              hipStream_t stream) {
    const float* x  = (const float*)d_in[0];
    const float* ew = (const float*)d_in[1];
    const float* Wq = (const float*)d_in[2];
    const float* bq = (const float*)d_in[3];
    const float* Wk = (const float*)d_in[4];
    const float* bk = (const float*)d_in[5];
    const float* Wv = (const float*)d_in[6];
    const float* bv = (const float*)d_in[7];
    const float* Wo = (const float*)d_in[8];
    const float* bo = (const float*)d_in[9];
    float* out = (float*)d_out;

    char* ws = (char*)d_ws;
    const size_t QSZ = (size_t)CBATCH * NHEAD * S_LEN * HDIM * sizeof(unsigned short); // 4 MiB
    const size_t PLANE_O = (size_t)CBATCH * NHEAD * S_LEN * HDIM * sizeof(float);      // 8 MiB
    const size_t PLANE_D = (size_t)CBATCH * NHEAD * S_LEN * sizeof(float);             // 256 KiB

    // choose NSPLIT by workspace capacity (deterministic: ws_size fixed per run)
    const size_t need4 = 3 * QSZ + 4 * PLANE_O + 4 * PLANE_D;
    const int ns = (ws_size >= need4) ? 4 : 2;

    unsigned short* Qw  = (unsigned short*)(ws);
    unsigned short* Kw  = (unsigned short*)(ws + QSZ);
    unsigned short* Vt2 = (unsigned short*)(ws + 2 * QSZ);
    unsigned short* Vw  = (unsigned short*)(ws + 3 * QSZ);
    float* partO = (float*)(ws + 3 * QSZ);                 // overlaps dead Vw
    float* den   = (float*)(ws + 3 * QSZ + (size_t)ns * PLANE_O);
    float* attnbuf = (float*)(ws);                          // overlaps dead Qw/Kw

    qkv_proj_kernel<<<dim3(256, 2, 3), 256, 0, stream>>>(x, Wq, bq, Wk, bk, Wv, bv, Qw, Kw, Vw);
    vtrans_kernel<<<dim3(S_LEN / 64, CBATCH * NHEAD), 256, 0, stream>>>(Vw, Vt2);
    if (ns == 4) {
        attn_kernel<4><<<dim3(S_LEN / 32, CBATCH, 4), 256, 0, stream>>>(Qw, Kw, Vt2, ew, partO, den);
        combine_kernel<4><<<dim3((CBATCH * S_LEN * HID / 4) / 256), 256, 0, stream>>>(partO, den, attnbuf);
    } else {
        attn_kernel<2><<<dim3(S_LEN / 32, CBATCH, 2), 256, 0, stream>>>(Qw, Kw, Vt2, ew, partO, den);
        combine_kernel<2><<<dim3((CBATCH * S_LEN * HID / 4) / 256), 256, 0, stream>>>(partO, den, attnbuf);
    }
    out_proj_kernel<<<dim3(256, 2), 256, 0, stream>>>(attnbuf, Wo, bo, out);
}

// Round 12
// 183.322 us; speedup vs baseline: 1.7568x; 1.1258x over previous
//
#include <hip/hip_runtime.h>
#include <hip/hip_bf16.h>
#include <cstdint>

#define S_LEN 4096
#define NHEAD 4
#define HDIM 32
#define HID 128
#define CBATCH 4
#define EPSW 1e-8f
#define NCHUNKS (S_LEN / 32)

typedef __attribute__((ext_vector_type(8))) short short8v;
typedef __attribute__((ext_vector_type(4))) float float4v;

__device__ __forceinline__ unsigned short f2bf(float f) {
    unsigned int u = __float_as_uint(f);
    return (unsigned short)((u + 0x7fffu + ((u >> 16) & 1u)) >> 16);
}

__device__ __forceinline__ float exp2_asm(float x) {
    float r;
    asm("v_exp_f32 %0, %1" : "=v"(r) : "v"(x));
    return r;
}

__device__ __forceinline__ unsigned cvt_pk_bf16(float lo, float hi) {
    unsigned r;
    asm("v_cvt_pk_bf16_f32 %0, %1, %2" : "=v"(r) : "v"(lo), "v"(hi));
    return r;
}

// async global->LDS, 16B per lane; LDS dest = wave-uniform base + lane*16
__device__ __forceinline__ void gload16(const void* g, void* l) {
    __builtin_amdgcn_global_load_lds(
        (const __attribute__((address_space(1))) void*)g,
        (__attribute__((address_space(3))) void*)l,
        16, 0, 0);
}

// ---------------------------------------------------------------------------
// Kernel 1: fused QKV projection.  out = (x @ W.T + b) [* SCALE*log2e for Q]
// ---------------------------------------------------------------------------
__global__ __launch_bounds__(256) void qkv_proj_kernel(
    const float* __restrict__ x,
    const float* __restrict__ Wq, const float* __restrict__ bq,
    const float* __restrict__ Wk, const float* __restrict__ bk,
    const float* __restrict__ Wv, const float* __restrict__ bv,
    unsigned short* __restrict__ Qo, unsigned short* __restrict__ Ko,
    unsigned short* __restrict__ Vo)
{
    __shared__ float xs[64][132];
    __shared__ float wsT[64][68];

    const int tid = threadIdx.x;
    const int mrow0 = blockIdx.x * 64;
    const int n0 = blockIdx.y * 64;
    const int p = blockIdx.z;
    const float* W    = (p == 0) ? Wq : (p == 1) ? Wk : Wv;
    const float* bias = (p == 0) ? bq : (p == 1) ? bk : bv;
    unsigned short* Out = (p == 0) ? Qo : (p == 1) ? Ko : Vo;

    for (int i = tid; i < 64 * 32; i += 256) {
        int r = i >> 5, c4 = (i & 31) * 4;
        *(float4*)&xs[r][c4] = *(const float4*)&x[(size_t)(mrow0 + r) * HID + c4];
    }

    float acc[4][4] = {};
    const int tr = tid >> 4;
    const int tc = tid & 15;

    for (int ph = 0; ph < 2; ++ph) {
        __syncthreads();
        for (int i = tid; i < 64 * 16; i += 256) {
            int r = i >> 4, c4 = (i & 15) * 4;
            float4 wv = *(const float4*)&W[(size_t)(n0 + r) * HID + ph * 64 + c4];
            wsT[c4 + 0][r] = wv.x;
            wsT[c4 + 1][r] = wv.y;
            wsT[c4 + 2][r] = wv.z;
            wsT[c4 + 3][r] = wv.w;
        }
        __syncthreads();
        #pragma unroll 4
        for (int k4 = 0; k4 < 16; ++k4) {
            float4 xv[4];
            #pragma unroll
            for (int i = 0; i < 4; ++i)
                xv[i] = *(const float4*)&xs[tr * 4 + i][ph * 64 + k4 * 4];
            #pragma unroll
            for (int kk = 0; kk < 4; ++kk) {
                float4 wv = *(const float4*)&wsT[k4 * 4 + kk][tc * 4];
                #pragma unroll
                for (int i = 0; i < 4; ++i) {
                    float xk = ((const float*)&xv[i])[kk];
                    acc[i][0] += xk * wv.x;
                    acc[i][1] += xk * wv.y;
                    acc[i][2] += xk * wv.z;
                    acc[i][3] += xk * wv.w;
                }
            }
        }
    }

    // SCALE * log2(e): exp(s*SCALE) == exp2(s * SCALE * log2e)
    const float scale = (p == 0) ? 0.25500544458521289f : 1.0f;
    float4 bv4 = *(const float4*)&bias[n0 + tc * 4];
    const int nbase = n0 + tc * 4;
    const int h = nbase >> 5;
    const int d = nbase & 31;
    #pragma unroll
    for (int i = 0; i < 4; ++i) {
        int m = mrow0 + tr * 4 + i;
        int c = m >> 12, s = m & 4095;
        unsigned short pk[4];
        pk[0] = f2bf((acc[i][0] + bv4.x) * scale);
        pk[1] = f2bf((acc[i][1] + bv4.y) * scale);
        pk[2] = f2bf((acc[i][2] + bv4.z) * scale);
        pk[3] = f2bf((acc[i][3] + bv4.w) * scale);
        *(uint2*)&Out[((size_t)(c * NHEAD + h) * S_LEN + s) * HDIM + d] = *(uint2*)pk;
    }
}

// ---------------------------------------------------------------------------
// Kernel 2: repack V (C,NH,S,HD) -> Vt2: exact PV A-fragment order.
// Vt2[((chh*2+db)*NCHUNKS + chunk)*512 + lane*8 + j] =
//    V[chh][key = chunk*32 + pi(g,j)][d = db*16 + li]
// where pi(g,j) = (j<4) ? 4g+j : 16+4g+(j-4)  — the SAME k-permutation the
// P-fragment uses, so the PV contraction is consistent.
// ---------------------------------------------------------------------------
__global__ __launch_bounds__(256) void vtrans_kernel(
    const unsigned short* __restrict__ V, unsigned short* __restrict__ Vt2)
{
    __shared__ unsigned short vs[64][40];
    const int tid = threadIdx.x;
    const int chh = blockIdx.y;
    const int s0 = blockIdx.x * 64;
    const size_t base = (size_t)chh * S_LEN * HDIM;
    {
        int r = tid >> 2, ch = (tid & 3) * 8;
        *(uint4*)&vs[r][ch] = *(const uint4*)&V[base + (size_t)(s0 + r) * HDIM + ch];
    }
    __syncthreads();
    {
        const int lchunk = tid >> 7;         // 0..1
        const int db = (tid >> 6) & 1;       // 0..1
        const int l = tid & 63;
        const int li = l & 15;
        const int g = l >> 4;
        unsigned short pk[8];
        #pragma unroll
        for (int j = 0; j < 8; ++j) {
            int key = lchunk * 32 + ((j < 4) ? (4 * g + j) : (16 + 4 * g + (j - 4)));
            pk[j] = vs[key][db * 16 + li];
        }
        size_t chunk = (size_t)(s0 >> 5) + lchunk;
        *(uint4*)&Vt2[(((size_t)chh * 2 + db) * NCHUNKS + chunk) * 512 + l * 8] = *(uint4*)pk;
    }
}

// ---------------------------------------------------------------------------
// Kernel 3: attention, split-K, LDS double-buffered via global_load_lds,
// fragment-order staging (r11) + COUNTED-vmcnt pipeline (T3/T4):
// the old __syncthreads() drained vmcnt(0) — waiting on loads issued the
// same iteration (zero hiding).  Now: raw s_barrier + s_waitcnt vmcnt(5)
// waits only for the PREVIOUS tranche; the 5 new loads stay in flight
// across the barrier.  WAR hazard covered by the top-of-iter barrier.
// NOTE: plain __launch_bounds__(256) — (256,4) was the r3/5/6/7 poison (r8).
// ---------------------------------------------------------------------------
template<int NS>
__global__ __launch_bounds__(256) void attn_kernel(
    const unsigned short* __restrict__ Q, const unsigned short* __restrict__ K,
    const unsigned short* __restrict__ Vt2, const float* __restrict__ ew,
    float* __restrict__ partO, float* __restrict__ den)
{
    const int KCHUNK = S_LEN / NS;
    const int NIT = KCHUNK / 32;

    __shared__ float ew_lds[2][1024];            // 2 x 4KB: 4 regions x 64 lanes x 4 floats
    __shared__ unsigned short k_lds[2][4096];    // 2 x 8KB: [wave][kf0|kf1][lane*8]
    __shared__ unsigned short v_lds[2][4096];    // 2 x 8KB: [wave][db0|db1][lane*8]

    const int tid = threadIdx.x;
    const int w = tid >> 6;          // head
    const int lane = tid & 63;
    const int li = lane & 15;
    const int g = lane >> 4;
    const int c = blockIdx.y;
    const int qbase = blockIdx.x * 32;
    const int split = blockIdx.z;
    const int kb0 = split * KCHUNK;
    const int chh = c * NHEAD + w;

    const size_t hb = (size_t)chh * S_LEN * HDIM;
    const unsigned short* Qh = Q + hb;
    const unsigned short* Kh = K + hb;
    const float* ewc = ew + (size_t)c * S_LEN * S_LEN;

    short8v qf0 = *(const short8v*)&Qh[(size_t)(qbase + li) * HDIM + g * 8];
    short8v qf1 = *(const short8v*)&Qh[(size_t)(qbase + 16 + li) * HDIM + g * 8];

    // ---- staging source pointers (per lane, fragment-order) ----
    const float* ew_src = ewc + (size_t)(qbase + (w >> 1) * 16 + li) * S_LEN + kb0
                        + (w & 1) * 16 + g * 4;
    const unsigned short* k_src = Kh + (size_t)(kb0 + li) * HDIM + g * 8;
    const unsigned short* v_src0 = Vt2 + (((size_t)chh * 2 + 0) * NCHUNKS + (kb0 >> 5)) * 512 + lane * 8;
    const unsigned short* v_src1 = Vt2 + (((size_t)chh * 2 + 1) * NCHUNKS + (kb0 >> 5)) * 512 + lane * 8;

    float4v o00 = {}, o01 = {}, o10 = {}, o11 = {};
    float den0 = 0.f, den1 = 0.f;
    const float4v zero4 = {0.f, 0.f, 0.f, 0.f};

    #define STAGE(b) do { \
        gload16(ew_src,              &ew_lds[b][w * 256]); \
        gload16(k_src,               &k_lds[b][w * 1024]); \
        gload16(k_src + 16 * HDIM,   &k_lds[b][w * 1024 + 512]); \
        gload16(v_src0,              &v_lds[b][w * 1024]); \
        gload16(v_src1,              &v_lds[b][w * 1024 + 512]); \
    } while (0)
    #define ADVANCE() do { ew_src += 32; k_src += 32 * HDIM; v_src0 += 512; v_src1 += 512; } while (0)
    #define CFENCE() asm volatile("" ::: "memory")

    STAGE(0);
    ADVANCE();

    int cur = 0;
    for (int it = 0; it < NIT; ++it) {
        if (it > 0) {
            // all waves finished READING buf[cur^1] (prev iter) before we
            // overwrite it below (WAR across waves)
            CFENCE();
            __builtin_amdgcn_s_barrier();
        }
        if (it + 1 < NIT) {
            STAGE(cur ^ 1);
            ADVANCE();
            // wait only for the PREVIOUS 5 loads (buf[cur]); the 5 just
            // issued stay in flight across the barrier
            asm volatile("s_waitcnt vmcnt(5)" ::: "memory");
        } else {
            asm volatile("s_waitcnt vmcnt(0)" ::: "memory");
        }
        __builtin_amdgcn_s_barrier();
        CFENCE();

        const unsigned short* kw = &k_lds[cur][w * 1024];
        const unsigned short* vw = &v_lds[cur][w * 1024];
        const float* eb = ew_lds[cur];

        short8v kf0 = *(const short8v*)&kw[lane * 8];
        short8v kf1 = *(const short8v*)&kw[512 + lane * 8];

        short8v vf0 = *(const short8v*)&vw[lane * 8];
        short8v vf1 = *(const short8v*)&vw[512 + lane * 8];

        float4 e00 = *(const float4*)&eb[lane * 4];
        float4 e01 = *(const float4*)&eb[256 + lane * 4];
        float4 e10 = *(const float4*)&eb[512 + lane * 4];
        float4 e11 = *(const float4*)&eb[768 + lane * 4];

        float4v s0 = __builtin_amdgcn_mfma_f32_16x16x32_bf16(kf0, qf0, zero4, 0, 0, 0);
        float4v s1 = __builtin_amdgcn_mfma_f32_16x16x32_bf16(kf1, qf0, zero4, 0, 0, 0);
        float4v s2 = __builtin_amdgcn_mfma_f32_16x16x32_bf16(kf0, qf1, zero4, 0, 0, 0);
        float4v s3 = __builtin_amdgcn_mfma_f32_16x16x32_bf16(kf1, qf1, zero4, 0, 0, 0);

        float p0 = fmaxf(e00.x, EPSW) * exp2_asm(s0[0]);
        float p1 = fmaxf(e00.y, EPSW) * exp2_asm(s0[1]);
        float p2 = fmaxf(e00.z, EPSW) * exp2_asm(s0[2]);
        float p3 = fmaxf(e00.w, EPSW) * exp2_asm(s0[3]);
        float p4 = fmaxf(e01.x, EPSW) * exp2_asm(s1[0]);
        float p5 = fmaxf(e01.y, EPSW) * exp2_asm(s1[1]);
        float p6 = fmaxf(e01.z, EPSW) * exp2_asm(s1[2]);
        float p7 = fmaxf(e01.w, EPSW) * exp2_asm(s1[3]);
        union { short8v v; unsigned u[4]; } pu0;
        pu0.u[0] = cvt_pk_bf16(p0, p1);
        pu0.u[1] = cvt_pk_bf16(p2, p3);
        pu0.u[2] = cvt_pk_bf16(p4, p5);
        pu0.u[3] = cvt_pk_bf16(p6, p7);
        den0 += ((p0 + p1) + (p2 + p3)) + ((p4 + p5) + (p6 + p7));
        o00 = __builtin_amdgcn_mfma_f32_16x16x32_bf16(vf0, pu0.v, o00, 0, 0, 0);
        o01 = __builtin_amdgcn_mfma_f32_16x16x32_bf16(vf1, pu0.v, o01, 0, 0, 0);

        float r0 = fmaxf(e10.x, EPSW) * exp2_asm(s2[0]);
        float r1 = fmaxf(e10.y, EPSW) * exp2_asm(s2[1]);
        float r2 = fmaxf(e10.z, EPSW) * exp2_asm(s2[2]);
        float r3 = fmaxf(e10.w, EPSW) * exp2_asm(s2[3]);
        float r4 = fmaxf(e11.x, EPSW) * exp2_asm(s3[0]);
        float r5 = fmaxf(e11.y, EPSW) * exp2_asm(s3[1]);
        float r6 = fmaxf(e11.z, EPSW) * exp2_asm(s3[2]);
        float r7 = fmaxf(e11.w, EPSW) * exp2_asm(s3[3]);
        union { short8v v; unsigned u[4]; } pu1;
        pu1.u[0] = cvt_pk_bf16(r0, r1);
        pu1.u[1] = cvt_pk_bf16(r2, r3);
        pu1.u[2] = cvt_pk_bf16(r4, r5);
        pu1.u[3] = cvt_pk_bf16(r6, r7);
        den1 += ((r0 + r1) + (r2 + r3)) + ((r4 + r5) + (r6 + r7));
        o10 = __builtin_amdgcn_mfma_f32_16x16x32_bf16(vf0, pu1.v, o10, 0, 0, 0);
        o11 = __builtin_amdgcn_mfma_f32_16x16x32_bf16(vf1, pu1.v, o11, 0, 0, 0);

        cur ^= 1;
    }
    #undef STAGE
    #undef ADVANCE
    #undef CFENCE

    den0 += __shfl_xor(den0, 16, 64);
    den0 += __shfl_xor(den0, 32, 64);
    den1 += __shfl_xor(den1, 16, 64);
    den1 += __shfl_xor(den1, 32, 64);

    const size_t pbase = (((size_t)split * CBATCH + c) * NHEAD + w) * S_LEN + qbase;
    {
        const size_t pb = pbase + li;
        float4 o;
        o.x = o00[0]; o.y = o00[1]; o.z = o00[2]; o.w = o00[3];
        *(float4*)&partO[pb * HDIM + 0 * 16 + g * 4] = o;
        o.x = o01[0]; o.y = o01[1]; o.z = o01[2]; o.w = o01[3];
        *(float4*)&partO[pb * HDIM + 1 * 16 + g * 4] = o;
        if (g == 0) den[pb] = den0;
    }
    {
        const size_t pb = pbase + 16 + li;
        float4 o;
        o.x = o10[0]; o.y = o10[1]; o.z = o10[2]; o.w = o10[3];
        *(float4*)&partO[pb * HDIM + 0 * 16 + g * 4] = o;
        o.x = o11[0]; o.y = o11[1]; o.z = o11[2]; o.w = o11[3];
        *(float4*)&partO[pb * HDIM + 1 * 16 + g * 4] = o;
        if (g == 0) den[pb] = den1;
    }
}

// ---------------------------------------------------------------------------
// Kernel 4: combine NS splits -> normalized attention output (C,S,HID) fp32.
// ---------------------------------------------------------------------------
template<int NS>
__global__ __launch_bounds__(256) void combine_kernel(
    const float* __restrict__ pO, const float* __restrict__ den,
    float* __restrict__ attnbuf)
{
    const int idx = blockIdx.x * 256 + threadIdx.x;
    const int d4 = idx & 7;
    const int q  = (idx >> 3) & (S_LEN - 1);
    const int h  = (idx >> 15) & 3;
    const int c  = idx >> 17;

    const size_t bq = ((size_t)c * NHEAD + h) * S_LEN + q;
    const size_t plane = (size_t)CBATCH * NHEAD * S_LEN;
    float4 acc = {0.f, 0.f, 0.f, 0.f};
    float dsum = 0.f;
    #pragma unroll
    for (int s = 0; s < NS; ++s) {
        const size_t b = (size_t)s * plane + bq;
        float4 a = *(const float4*)&pO[b * HDIM + d4 * 4];
        acc.x += a.x; acc.y += a.y; acc.z += a.z; acc.w += a.w;
        dsum += den[b];
    }
    float inv = 1.0f / dsum;
    float4 o;
    o.x = acc.x * inv;
    o.y = acc.y * inv;
    o.z = acc.z * inv;
    o.w = acc.w * inv;
    *(float4*)&attnbuf[((size_t)c * S_LEN + q) * HID + h * HDIM + d4 * 4] = o;
}

// ---------------------------------------------------------------------------
// Kernel 5: output projection. out = attnbuf @ Wo.T + bo   (all fp32)
// ---------------------------------------------------------------------------
__global__ __launch_bounds__(256) void out_proj_kernel(
    const float* __restrict__ ain, const float* __restrict__ Wo,
    const float* __restrict__ bo, float* __restrict__ out)
{
    __shared__ float xs[64][132];
    __shared__ float wsT[64][68];

    const int tid = threadIdx.x;
    const int mrow0 = blockIdx.x * 64;
    const int n0 = blockIdx.y * 64;

    for (int i = tid; i < 64 * 32; i += 256) {
        int r = i >> 5, c4 = (i & 31) * 4;
        *(float4*)&xs[r][c4] = *(const float4*)&ain[(size_t)(mrow0 + r) * HID + c4];
    }

    float acc[4][4] = {};
    const int tr = tid >> 4;
    const int tc = tid & 15;

    for (int ph = 0; ph < 2; ++ph) {
        __syncthreads();
        for (int i = tid; i < 64 * 16; i += 256) {
            int r = i >> 4, c4 = (i & 15) * 4;
            float4 wv = *(const float4*)&Wo[(size_t)(n0 + r) * HID + ph * 64 + c4];
            wsT[c4 + 0][r] = wv.x;
            wsT[c4 + 1][r] = wv.y;
            wsT[c4 + 2][r] = wv.z;
            wsT[c4 + 3][r] = wv.w;
        }
        __syncthreads();
        #pragma unroll 4
        for (int k4 = 0; k4 < 16; ++k4) {
            float4 xv[4];
            #pragma unroll
            for (int i = 0; i < 4; ++i)
                xv[i] = *(const float4*)&xs[tr * 4 + i][ph * 64 + k4 * 4];
            #pragma unroll
            for (int kk = 0; kk < 4; ++kk) {
                float4 wv = *(const float4*)&wsT[k4 * 4 + kk][tc * 4];
                #pragma unroll
                for (int i = 0; i < 4; ++i) {
                    float xk = ((const float*)&xv[i])[kk];
                    acc[i][0] += xk * wv.x;
                    acc[i][1] += xk * wv.y;
                    acc[i][2] += xk * wv.z;
                    acc[i][3] += xk * wv.w;
                }
            }
        }
    }

    float4 bv4 = *(const float4*)&bo[n0 + tc * 4];
    #pragma unroll
    for (int i = 0; i < 4; ++i) {
        int m = mrow0 + tr * 4 + i;
        float4 o;
        o.x = acc[i][0] + bv4.x;
        o.y = acc[i][1] + bv4.y;
        o.z = acc[i][2] + bv4.z;
        o.w = acc[i][3] + bv4.w;
        *(float4*)&out[(size_t)m * HID + n0 + tc * 4] = o;
    }
}

extern "C" void kernel_launch(void* const* d_in, const int* in_sizes, int n_in,
                              void* d_out, int out_size, void* d_ws, size_t ws_size,
                              hipStream_t stream) {
    const float* x  = (const float*)d_in[0];
    const float* ew = (const float*)d_in[1];
    const float* Wq = (const float*)d_in[2];
    const float* bq = (const float*)d_in[3];
    const float* Wk = (const float*)d_in[4];
    const float* bk = (const float*)d_in[5];
    const float* Wv = (const float*)d_in[6];
    const float* bv = (const float*)d_in[7];
    const float* Wo = (const float*)d_in[8];
    const float* bo = (const float*)d_in[9];
    float* out = (float*)d_out;

    char* ws = (char*)d_ws;
    const size_t QSZ = (size_t)CBATCH * NHEAD * S_LEN * HDIM * sizeof(unsigned short); // 4 MiB
    const size_t PLANE_O = (size_t)CBATCH * NHEAD * S_LEN * HDIM * sizeof(float);      // 8 MiB
    const size_t PLANE_D = (size_t)CBATCH * NHEAD * S_LEN * sizeof(float);             // 256 KiB

    // choose NSPLIT by workspace capacity (deterministic: ws_size fixed per run)
    const size_t need4 = 3 * QSZ + 4 * PLANE_O + 4 * PLANE_D;
    const int ns = (ws_size >= need4) ? 4 : 2;

    unsigned short* Qw  = (unsigned short*)(ws);
    unsigned short* Kw  = (unsigned short*)(ws + QSZ);
    unsigned short* Vt2 = (unsigned short*)(ws + 2 * QSZ);
    unsigned short* Vw  = (unsigned short*)(ws + 3 * QSZ);
    float* partO = (float*)(ws + 3 * QSZ);                 // overlaps dead Vw
    float* den   = (float*)(ws + 3 * QSZ + (size_t)ns * PLANE_O);
    float* attnbuf = (float*)(ws);                          // overlaps dead Qw/Kw

    qkv_proj_kernel<<<dim3(256, 2, 3), 256, 0, stream>>>(x, Wq, bq, Wk, bk, Wv, bv, Qw, Kw, Vw);
    vtrans_kernel<<<dim3(S_LEN / 64, CBATCH * NHEAD), 256, 0, stream>>>(Vw, Vt2);
    if (ns == 4) {
        attn_kernel<4><<<dim3(S_LEN / 32, CBATCH, 4), 256, 0, stream>>>(Qw, Kw, Vt2, ew, partO, den);
        combine_kernel<4><<<dim3((CBATCH * S_LEN * HID / 4) / 256), 256, 0, stream>>>(partO, den, attnbuf);
    } else {
        attn_kernel<2><<<dim3(S_LEN / 32, CBATCH, 2), 256, 0, stream>>>(Qw, Kw, Vt2, ew, partO, den);
        combine_kernel<2><<<dim3((CBATCH * S_LEN * HID / 4) / 256), 256, 0, stream>>>(partO, den, attnbuf);
    }
    out_proj_kernel<<<dim3(256, 2), 256, 0, stream>>>(attnbuf, Wo, bo, out);
}